// Round 15
// baseline (4261.937 us; speedup 1.0000x reference)
//
#include <hip/hip_runtime.h>
#include <hip/hip_bf16.h>
#include <cstdint>

// RateModel: h_{s+1} = tanh(W_rec h_s + b_rec + W_in x_s); out = W_out h + b_out
// B=32, Nt=2000 (sequential), N=512, N_in=128, N_out=64.
//
// k_scan R15 = R13 protocol/schedule (proven: 3247us) with HALVED SYNC FAN-IN:
// 32 WGs = 8 groups x 4 row-slices (128 rows each; was 8x64). Each wave holds
// TWO 16-row A-frag tiles (128 VGPR; 4 waves/CU = 1/SIMD, 512-VGPR budget).
// Fewer producers per group (4 vs 8) shrinks the __all tail; 32 pollers halve
// MALL traffic. delta=s_sleep 5 and the strict issue->vmcnt(0)->check retry
// are R13-verbatim (R14 falsified longer delay + divergent retry).
// Protocol (R4/R11/R13-proven): 4B atoms [hi16|lo13|tag3], tag=step&7,
// sc0 sc1 (MALL, any WG placement); skew<=1 => stale tag differs by 2 mod 8
// => never false-validates; Hex memsetAsync(0) per launch. Deterministic,
// replay-safe (stale exact-match data from identical prior replay is
// bit-identical). h = hi+lo13 bf16 -> 2 MFMA passes; one barrier/step.

#define NB   32
#define NT   2000
#define NIN  128
#define NN   512
#define NOUT 64
#define NBNN (NB * NN)
#define PAR  65536            // bytes per parity slot (u32[32][512])

typedef unsigned short u16;
typedef unsigned int   u32;
typedef unsigned long long u64;
typedef __bf16 bf16x8 __attribute__((ext_vector_type(8)));
typedef float  f32x4  __attribute__((ext_vector_type(4)));
typedef u32    u32x4  __attribute__((ext_vector_type(4)));

static __device__ __forceinline__ u16 f2bf(float f) {
  return __builtin_bit_cast(u16, (__bf16)f);   // RNE
}
static __device__ __forceinline__ float bf2f(u16 u) {
  return (float)__builtin_bit_cast(__bf16, u);
}
static __device__ __forceinline__ void split_hl(float f, u16& hi, u16& lo) {
  const u32 u = __float_as_uint(f);
  hi = (u16)(u >> 16);                                   // truncated bf16
  lo = f2bf(f - __uint_as_float(u & 0xffff0000u));       // residual
}
static __device__ __forceinline__ float fast_tanh(float x) {
  const float xc = fminf(fmaxf(x, -12.f), 12.f);
  const float t = __builtin_amdgcn_exp2f(xc * 2.8853900817779268f); // 2*log2(e)
  return (t - 1.f) * __builtin_amdgcn_rcpf(t + 1.f);
}

// device-scope (MALL) 16B ops; vmcnt-only, invisible to compiler's wait model
static __device__ __forceinline__ u32x4 ld_dev16(const void* p) {
  u32x4 r;
  asm volatile("global_load_dwordx4 %0, %1, off sc0 sc1" : "=v"(r) : "v"(p) : "memory");
  return r;
}
static __device__ __forceinline__ void st_dev16(void* p, u32x4 v) {
  asm volatile("global_store_dwordx4 %0, %1, off sc0 sc1" :: "v"(p), "v"(v) : "memory");
}
static __device__ __forceinline__ void ld_u16a(u32& d, const void* p) {
  asm volatile("global_load_ushort %0, %1, off" : "=v"(d) : "v"(p) : "memory");
}
static __device__ __forceinline__ bool tags8(u32x4 a, u32x4 b, u32 want) {
  return ((a.x & 7u) == want) & ((a.y & 7u) == want) &
         ((a.z & 7u) == want) & ((a.w & 7u) == want) &
         ((b.x & 7u) == want) & ((b.y & 7u) == want) &
         ((b.z & 7u) == want) & ((b.w & 7u) == want);
}

// ---------------- prep: bf16 weight tables --------------------------------
__global__ __launch_bounds__(256) void k_prep_in(const float* __restrict__ Win,
                                                 u16* __restrict__ winh) {
  const int e = blockIdx.x * 256 + threadIdx.x;
  if (e < NN * NIN) winh[e] = f2bf(Win[e]);
}
__global__ __launch_bounds__(256) void k_prep_out(const float* __restrict__ Wout,
                                                  u16* __restrict__ wouth) {
  const int e = blockIdx.x * 256 + threadIdx.x;
  if (e < NOUT * NN) wouth[e] = f2bf(Wout[e]);
}

// ---------------- K1 (MFMA): jx[t][b][n] = sum_k x[b][t][k] * Win[n][k] ----
__global__ __launch_bounds__(256) void k_in(const float* __restrict__ x,
                                            const u16* __restrict__ winh,
                                            u16* __restrict__ jx) {
  const int t = blockIdx.x;
  const int tid = threadIdx.x;
  const int wv = tid >> 6, lane = tid & 63;
  __shared__ u16 Xh[NB][136];
  __shared__ u16 Xl[NB][136];
  {
    const int b = tid >> 3, k0 = (tid & 7) * 16;
    const float* xp = x + ((size_t)b * NT + t) * NIN + k0;
    u16 hb[16], lb[16];
#pragma unroll
    for (int j = 0; j < 16; ++j) split_hl(xp[j], hb[j], lb[j]);
    *(uint4*)&Xh[b][k0]     = *(uint4*)&hb[0];
    *(uint4*)&Xh[b][k0 + 8] = *(uint4*)&hb[8];
    *(uint4*)&Xl[b][k0]     = *(uint4*)&lb[0];
    *(uint4*)&Xl[b][k0 + 8] = *(uint4*)&lb[8];
  }
  __syncthreads();

  const int r15 = lane & 15, kg = lane >> 4;
  const int n0 = 128 * wv;
  f32x4 acc[2][8];
#pragma unroll
  for (int mt = 0; mt < 2; ++mt)
#pragma unroll
    for (int nt = 0; nt < 8; ++nt) acc[mt][nt] = (f32x4){0.f, 0.f, 0.f, 0.f};

#pragma unroll
  for (int kt = 0; kt < 4; ++kt) {
    const int ko = 32 * kt + 8 * kg;
    const bf16x8 ah0 = *(const bf16x8*)&Xh[r15][ko];
    const bf16x8 ah1 = *(const bf16x8*)&Xh[16 + r15][ko];
    const bf16x8 al0 = *(const bf16x8*)&Xl[r15][ko];
    const bf16x8 al1 = *(const bf16x8*)&Xl[16 + r15][ko];
#pragma unroll
    for (int nt = 0; nt < 8; ++nt) {
      const int n = n0 + 16 * nt + r15;
      const bf16x8 bh = *(const bf16x8*)(winh + (size_t)n * NIN + ko);
      acc[0][nt] = __builtin_amdgcn_mfma_f32_16x16x32_bf16(ah0, bh, acc[0][nt], 0, 0, 0);
      acc[1][nt] = __builtin_amdgcn_mfma_f32_16x16x32_bf16(ah1, bh, acc[1][nt], 0, 0, 0);
      acc[0][nt] = __builtin_amdgcn_mfma_f32_16x16x32_bf16(al0, bh, acc[0][nt], 0, 0, 0);
      acc[1][nt] = __builtin_amdgcn_mfma_f32_16x16x32_bf16(al1, bh, acc[1][nt], 0, 0, 0);
    }
  }
#pragma unroll
  for (int mt = 0; mt < 2; ++mt)
#pragma unroll
    for (int nt = 0; nt < 8; ++nt) {
      const int n = n0 + 16 * nt + r15;
#pragma unroll
      for (int r = 0; r < 4; ++r) {
        const int b = 16 * mt + 4 * kg + r;
        jx[((size_t)t * NB + b) * NN + n] = f2bf(acc[mt][nt][r]);
      }
    }
}

// ---------------- K2: sequential scan (32 WGs, 128 rows each) --------------
__global__ __launch_bounds__(256) void k_scan(const float* __restrict__ Wrec,
                                              const float* __restrict__ brec,
                                              const u16* __restrict__ jx,
                                              u32* Hex,             // [2][NB][NN] 4B atoms
                                              u16* __restrict__ Hh) // [NT][NB][NN]
{
  const int wg = blockIdx.x;          // 32 WGs
  const int g = wg & 7;               // chain group (chains 4g..4g+3)
  const int i = wg >> 3;              // row slice 0..3: rows [128i, 128i+128)
  const int tid = threadIdx.x;
  const int wv = tid >> 6, lane = tid & 63;

  // stride 528 u16 = 264 dw == 8 (mod 32): B-frag ds_read_b128 2-way -> free (m136)
  __shared__ u16 SHhi[2][4][528];
  __shared__ u16 SHlo[2][4][528];
  __shared__ float Pj[2][4][128];

  const int r15 = lane & 15, kg = lane >> 4;
  const int t64 = tid & 63;
  const float brv0 = brec[128 * i + t64];
  const float brv1 = brec[128 * i + 64 + t64];

  // resident A-frags: TWO 16-row tiles per wave; row = lane&15, k = 8*kg+j
  const int arow0 = 128 * i + 32 * wv + r15;        // tile0
  bf16x8 afrag0[16], afrag1[16];
#pragma unroll
  for (int kt = 0; kt < 16; ++kt) {
    const float* wp0 = Wrec + (size_t)arow0 * NN + 32 * kt + 8 * kg;
    const float* wp1 = wp0 + (size_t)16 * NN;       // tile1 = tile0 + 16 rows
    bf16x8 a0, a1;
#pragma unroll
    for (int j = 0; j < 8; ++j) { a0[j] = (__bf16)wp0[j]; a1[j] = (__bf16)wp1[j]; }
    afrag0[kt] = a0;
    afrag1[kt] = a1;
  }

  const int sc = wv;                 // staged chain (== wave)
  const int cc = r15;                // D col = chain (valid < 4)
  const int rb0 = 32 * wv + 4 * kg;  // LOCAL row base, tile0 (0..127)
  const int gch = 4 * g + cc;
  const int ro0 = 128 * i + rb0;     // global rows tile0: ro0..ro0+3
  const bool ownrow = ((t64 >> 4) == i);  // polled rows 8t64..+7 in own slice

  char* HexB_ = (char*)Hex;
  // consumer: rows 8*t64..+7 of chain sc -> 32B contiguous
  const char* cb = HexB_ + ((size_t)(4 * g + sc) * NN + 8 * t64) * 4;
  // producer: tile0 rows ro0..+3 (16B), tile1 at +16 rows (+64B)
  char* pb = HexB_ + ((size_t)gch * NN + ro0) * 4;

  const char* jp = (const char*)jx + ((size_t)(NB + 4 * g + sc) * NN + 128 * i + t64) * 2;
  u16* hb = Hh + (size_t)gch * NN + ro0;

  const float jxv00 = bf2f(jx[(size_t)(4 * g + sc) * NN + 128 * i + t64]);
  const float jxv01 = bf2f(jx[(size_t)(4 * g + sc) * NN + 128 * i + 64 + t64]);
  u32 jxu0 = 0, jxu1 = 0;

  for (int s = 0; s < NT; ++s) {
    const int slot = s & 1;
    if (s > 0) {
      // R13-proven: s_sleep 5 then strictly RTT-serialized poll rounds
      asm volatile("s_sleep 5" :::);
      const char* cbs = cb + (slot ? PAR : 0);
      const u32 want = (u32)s & 7u;
      u32x4 A0 = ld_dev16(cbs);
      u32x4 A1 = ld_dev16(cbs + 16);
      asm volatile("s_waitcnt vmcnt(0)" ::: "memory");  // also drains jx + acks
      __builtin_amdgcn_sched_barrier(0);
      bool ok = ownrow | tags8(A0, A1, want);
      int guard = 1 << 16;                               // anti-hang only
      while (!__all(ok) && --guard) {
        A0 = ld_dev16(cbs);
        A1 = ld_dev16(cbs + 16);
        asm volatile("s_waitcnt vmcnt(0)" ::: "memory");
        __builtin_amdgcn_sched_barrier(0);
        ok = ownrow | tags8(A0, A1, want);
      }
      if (!ownrow) {
        // unpack: atom = [hi16 | lo13 | tag3]; rows ascend A0.x..A1.w
        const u32x4 hw = {(A0.x >> 16) | (A0.y & 0xffff0000u),
                          (A0.z >> 16) | (A0.w & 0xffff0000u),
                          (A1.x >> 16) | (A1.y & 0xffff0000u),
                          (A1.z >> 16) | (A1.w & 0xffff0000u)};
        const u32x4 lw = {(A0.x & 0xfff8u) | ((A0.y & 0xfff8u) << 16),
                          (A0.z & 0xfff8u) | ((A0.w & 0xfff8u) << 16),
                          (A1.x & 0xfff8u) | ((A1.y & 0xfff8u) << 16),
                          (A1.z & 0xfff8u) | ((A1.w & 0xfff8u) << 16)};
        *(u32x4*)&SHhi[slot][sc][8 * t64] = hw;
        *(u32x4*)&SHlo[slot][sc][8 * t64] = lw;
      }
      Pj[slot][sc][t64]      = __uint_as_float(jxu0 << 16) + brv0;
      Pj[slot][sc][t64 + 64] = __uint_as_float(jxu1 << 16) + brv1;
    } else {
      Pj[0][sc][t64]      = jxv00 + brv0;
      Pj[0][sc][t64 + 64] = jxv01 + brv1;
    }

    // single barrier per step: drains only LDS writes (globals are vmcnt-only)
    asm volatile("s_waitcnt lgkmcnt(0)" ::: "memory");
    __builtin_amdgcn_s_barrier();
    __builtin_amdgcn_sched_barrier(0);

    // 8 independent MFMA chains: 2 row-tiles x hi/lo x K-halves
    f32x4 t0h0 = {0.f, 0.f, 0.f, 0.f}, t0h1 = {0.f, 0.f, 0.f, 0.f};
    f32x4 t0l0 = {0.f, 0.f, 0.f, 0.f}, t0l1 = {0.f, 0.f, 0.f, 0.f};
    f32x4 t1h0 = {0.f, 0.f, 0.f, 0.f}, t1h1 = {0.f, 0.f, 0.f, 0.f};
    f32x4 t1l0 = {0.f, 0.f, 0.f, 0.f}, t1l1 = {0.f, 0.f, 0.f, 0.f};
    if (s > 0) {
      const int c4 = cc & 3;
#pragma unroll
      for (int kt = 0; kt < 8; ++kt) {
        const int ko  = 32 * kt + 8 * kg;
        const int ko2 = 32 * (kt + 8) + 8 * kg;
        const bf16x8 bh0 = *(const bf16x8*)&SHhi[slot][c4][ko];
        const bf16x8 bh1 = *(const bf16x8*)&SHhi[slot][c4][ko2];
        const bf16x8 bl0 = *(const bf16x8*)&SHlo[slot][c4][ko];
        const bf16x8 bl1 = *(const bf16x8*)&SHlo[slot][c4][ko2];
        t0h0 = __builtin_amdgcn_mfma_f32_16x16x32_bf16(afrag0[kt],     bh0, t0h0, 0, 0, 0);
        t1h0 = __builtin_amdgcn_mfma_f32_16x16x32_bf16(afrag1[kt],     bh0, t1h0, 0, 0, 0);
        t0h1 = __builtin_amdgcn_mfma_f32_16x16x32_bf16(afrag0[kt + 8], bh1, t0h1, 0, 0, 0);
        t1h1 = __builtin_amdgcn_mfma_f32_16x16x32_bf16(afrag1[kt + 8], bh1, t1h1, 0, 0, 0);
        t0l0 = __builtin_amdgcn_mfma_f32_16x16x32_bf16(afrag0[kt],     bl0, t0l0, 0, 0, 0);
        t1l0 = __builtin_amdgcn_mfma_f32_16x16x32_bf16(afrag1[kt],     bl0, t1l0, 0, 0, 0);
        t0l1 = __builtin_amdgcn_mfma_f32_16x16x32_bf16(afrag0[kt + 8], bl1, t0l1, 0, 0, 0);
        t1l1 = __builtin_amdgcn_mfma_f32_16x16x32_bf16(afrag1[kt + 8], bl1, t1l1, 0, 0, 0);
      }
    }
    const f32x4 accT0 = (t0h0 + t0h1) + (t0l0 + t0l1);
    const f32x4 accT1 = (t1h0 + t1h1) + (t1l0 + t1l1);

    // epilogue: publish both tiles FIRST, self-stage own rows, Hh, jx prefetch
    const int nsl = (s + 1) & 1;
    if (cc < 4) {
      const u32 tg = (u32)(s + 1) & 7u;
      u32 at0[4], at1[4];
      u16 hp0[4], lp0[4], hp1[4], lp1[4];
#pragma unroll
      for (int r = 0; r < 4; ++r) {
        const float pre0 = accT0[r] + Pj[slot][cc][rb0 + r];
        const float h0 = fast_tanh(pre0);
        const u32 uh0 = __float_as_uint(h0);
        lp0[r] = (u16)(f2bf(h0 - __uint_as_float(uh0 & 0xffff0000u)) & 0xfff8u);
        hp0[r] = (u16)(uh0 >> 16);
        at0[r] = (uh0 & 0xffff0000u) | (u32)lp0[r] | tg;
        const float pre1 = accT1[r] + Pj[slot][cc][rb0 + 16 + r];
        const float h1 = fast_tanh(pre1);
        const u32 uh1 = __float_as_uint(h1);
        lp1[r] = (u16)(f2bf(h1 - __uint_as_float(uh1 & 0xffff0000u)) & 0xfff8u);
        hp1[r] = (u16)(uh1 >> 16);
        at1[r] = (uh1 & 0xffff0000u) | (u32)lp1[r] | tg;
      }
      char* pbs = pb + (nsl ? PAR : 0);
      st_dev16(pbs,      (u32x4){at0[0], at0[1], at0[2], at0[3]});
      st_dev16(pbs + 64, (u32x4){at1[0], at1[1], at1[2], at1[3]});
      // self-stage own rows into next-slot LDS (never polled; same lo13 values)
      uint2 hw0, lw0, hw1, lw1;
      hw0.x = (u32)hp0[0] | ((u32)hp0[1] << 16);
      hw0.y = (u32)hp0[2] | ((u32)hp0[3] << 16);
      lw0.x = (u32)lp0[0] | ((u32)lp0[1] << 16);
      lw0.y = (u32)lp0[2] | ((u32)lp0[3] << 16);
      hw1.x = (u32)hp1[0] | ((u32)hp1[1] << 16);
      hw1.y = (u32)hp1[2] | ((u32)hp1[3] << 16);
      lw1.x = (u32)lp1[0] | ((u32)lp1[1] << 16);
      lw1.y = (u32)lp1[2] | ((u32)lp1[3] << 16);
      *(uint2*)&SHhi[nsl][cc][ro0]      = hw0;
      *(uint2*)&SHlo[nsl][cc][ro0]      = lw0;
      *(uint2*)&SHhi[nsl][cc][ro0 + 16] = hw1;
      *(uint2*)&SHlo[nsl][cc][ro0 + 16] = lw1;
      *(uint2*)hb        = hw0;
      *(uint2*)(hb + 16) = hw1;
    }
    hb += NBNN;

    // jx prefetch for next step (different addresses; no poll hazard)
    if (s + 1 < NT) {
      ld_u16a(jxu0, jp);
      ld_u16a(jxu1, jp + 128);
      jp += 2 * NBNN;
    }
  }
}

// ---------------- K3 (MFMA): out[b][t][o] = sum_n Hh[t][b][n]*Wout[o][n] + bout[o]
__global__ __launch_bounds__(256) void k_out(const u16* __restrict__ Hh,
                                             const u16* __restrict__ wouth,
                                             const float* __restrict__ bout,
                                             float* __restrict__ out) {
  const int t = blockIdx.x;
  const int tid = threadIdx.x;
  const int wv = tid >> 6, lane = tid & 63;
  __shared__ u16 Ah[NB][528];
  {
    const int b = tid >> 3, k0 = (tid & 7) * 64;
    const u16* hp = Hh + ((size_t)t * NB + b) * NN + k0;
#pragma unroll
    for (int j = 0; j < 8; ++j)
      *(uint4*)&Ah[b][k0 + 8 * j] = *(const uint4*)(hp + 8 * j);
  }
  __syncthreads();

  const int r15 = lane & 15, kg = lane >> 4;
  const int o = 16 * wv + r15;
  f32x4 acc[2] = {{0.f, 0.f, 0.f, 0.f}, {0.f, 0.f, 0.f, 0.f}};
#pragma unroll
  for (int kt = 0; kt < 16; ++kt) {
    const int ko = 32 * kt + 8 * kg;
    const bf16x8 b0 = *(const bf16x8*)(wouth + (size_t)o * NN + ko);
    const bf16x8 a0 = *(const bf16x8*)&Ah[r15][ko];
    const bf16x8 a1 = *(const bf16x8*)&Ah[16 + r15][ko];
    acc[0] = __builtin_amdgcn_mfma_f32_16x16x32_bf16(a0, b0, acc[0], 0, 0, 0);
    acc[1] = __builtin_amdgcn_mfma_f32_16x16x32_bf16(a1, b0, acc[1], 0, 0, 0);
  }
  const float bo = bout[o];
#pragma unroll
  for (int mt = 0; mt < 2; ++mt)
#pragma unroll
    for (int r = 0; r < 4; ++r) {
      const int b = 16 * mt + 4 * kg + r;
      out[((size_t)b * NT + t) * NOUT + o] = acc[mt][r] + bo;
    }
}

// ---------------- launch ----------------------------------------------------
// ws: [0, 65,536,000)             jx bf16 [NT][NB][NN]  (post-scan: wouth @ +0)
//     [65,536,000, 131,072,000)   Hh bf16 [NT][NB][NN]  (pre-scan: winh @ +0)
//     [131,072,000, 131,203,072)  Hex u32 [2][NB][NN]   (4B self-tagged atoms)
extern "C" void kernel_launch(void* const* d_in, const int* in_sizes, int n_in,
                              void* d_out, int out_size, void* d_ws, size_t ws_size,
                              hipStream_t stream) {
  (void)in_sizes; (void)n_in; (void)out_size;
  const float* x    = (const float*)d_in[0];
  const float* Wrec = (const float*)d_in[1];
  const float* brec = (const float*)d_in[2];
  const float* Win  = (const float*)d_in[3];
  const float* Wout = (const float*)d_in[4];
  const float* bout = (const float*)d_in[5];
  float* out = (float*)d_out;

  if (ws_size < 131203072ULL) return;  // visible failure beacon

  char* ws = (char*)d_ws;
  u16* jx    = (u16*)ws;
  u16* Hh    = (u16*)(ws + 65536000);
  u32* Hex   = (u32*)(ws + 131072000);
  u16* winh  = (u16*)(ws + 65536000);  // overlays Hh (dead until k_scan)
  u16* wouth = (u16*)ws;               // overlays jx (dead after k_scan)

  hipMemsetAsync(Hex, 0, 2 * PAR, stream);   // kill poison/cross-launch tag aliases
  k_prep_in<<<dim3((NN * NIN + 255) / 256), dim3(256), 0, stream>>>(Win, winh);
  k_in<<<dim3(NT), dim3(256), 0, stream>>>(x, winh, jx);
  k_scan<<<dim3(32), dim3(256), 0, stream>>>(Wrec, brec, jx, Hex, Hh);
  k_prep_out<<<dim3((NOUT * NN + 255) / 256), dim3(256), 0, stream>>>(Wout, wouth);
  k_out<<<dim3(NT), dim3(256), 0, stream>>>(Hh, wouth, bout, out);
}

// Round 16
// 3286.974 us; speedup vs baseline: 1.2966x; 1.2966x over previous
//
#include <hip/hip_runtime.h>
#include <hip/hip_bf16.h>
#include <cstdint>

// RateModel: h_{s+1} = tanh(W_rec h_s + b_rec + W_in x_s); out = W_out h + b_out
// B=32, Nt=2000 (sequential), N=512, N_in=128, N_out=64.
//
// k_scan R16 = R13 (proven best: 3247us; 64 WGs = 8 groups x 8 row-slices,
// 256 thr, one 16-row A-tile/wave) + two micro-deltas:
//  - s_sleep 5 -> 3: first MALL sample at ~642cy > ~600cy peer-commit window
//    (R11/R13/R14 sweep: sleep 0/320/640 -> 3890/3247/3331; minimum is just
//    past commit). Saves ~128cy/step if hit rate holds; FETCH_SIZE is the
//    miss-rate diagnostic.
//  - line-atomic tag check: a 16B store is one MALL transaction, so atom 0's
//    tag validates its whole 16B line -> check 2 tags instead of 8.
// R15 (128-row WGs) falsified the fan-in theory: FETCH flat, occupancy
// collapsed -> reverted. R14 falsified longer-delay + divergent retry.
// Protocol (R4/R11/R13-proven): 4B atoms [hi16|lo13|tag3], tag=step&7,
// sc0 sc1 (MALL, correct for ANY WG placement); skew<=1 => stale tag differs
// by 2 mod 8 => never false-validates; Hex memsetAsync(0) per launch kills
// poison/cross-launch aliases. Polls STRICTLY issue->vmcnt(0)->check (R10:
// overlapped same-address polls MSHR-merge -> livelock; R12: in-flight asm
// dests must not cross control flow). Deterministic, replay-safe.

#define NB   32
#define NT   2000
#define NIN  128
#define NN   512
#define NOUT 64
#define NBNN (NB * NN)
#define PAR  65536            // bytes per parity slot (u32[32][512])

typedef unsigned short u16;
typedef unsigned int   u32;
typedef unsigned long long u64;
typedef __bf16 bf16x8 __attribute__((ext_vector_type(8)));
typedef float  f32x4  __attribute__((ext_vector_type(4)));
typedef u32    u32x4  __attribute__((ext_vector_type(4)));

static __device__ __forceinline__ u16 f2bf(float f) {
  return __builtin_bit_cast(u16, (__bf16)f);   // RNE
}
static __device__ __forceinline__ float bf2f(u16 u) {
  return (float)__builtin_bit_cast(__bf16, u);
}
static __device__ __forceinline__ void split_hl(float f, u16& hi, u16& lo) {
  const u32 u = __float_as_uint(f);
  hi = (u16)(u >> 16);                                   // truncated bf16
  lo = f2bf(f - __uint_as_float(u & 0xffff0000u));       // residual
}
static __device__ __forceinline__ float fast_tanh(float x) {
  const float xc = fminf(fmaxf(x, -12.f), 12.f);
  const float t = __builtin_amdgcn_exp2f(xc * 2.8853900817779268f); // 2*log2(e)
  return (t - 1.f) * __builtin_amdgcn_rcpf(t + 1.f);
}

// device-scope (MALL) 16B ops; vmcnt-only, invisible to compiler's wait model
static __device__ __forceinline__ u32x4 ld_dev16(const void* p) {
  u32x4 r;
  asm volatile("global_load_dwordx4 %0, %1, off sc0 sc1" : "=v"(r) : "v"(p) : "memory");
  return r;
}
static __device__ __forceinline__ void st_dev16(void* p, u32x4 v) {
  asm volatile("global_store_dwordx4 %0, %1, off sc0 sc1" :: "v"(p), "v"(v) : "memory");
}
static __device__ __forceinline__ void ld_u16a(u32& d, const void* p) {
  asm volatile("global_load_ushort %0, %1, off" : "=v"(d) : "v"(p) : "memory");
}
// line-atomic: one tag per 16B line suffices (16B store = 1 MALL transaction)
static __device__ __forceinline__ bool tags2(u32x4 a, u32x4 b, u32 want) {
  return ((a.x & 7u) == want) & ((b.x & 7u) == want);
}

// ---------------- prep: bf16 weight tables --------------------------------
__global__ __launch_bounds__(256) void k_prep_in(const float* __restrict__ Win,
                                                 u16* __restrict__ winh) {
  const int e = blockIdx.x * 256 + threadIdx.x;
  if (e < NN * NIN) winh[e] = f2bf(Win[e]);
}
__global__ __launch_bounds__(256) void k_prep_out(const float* __restrict__ Wout,
                                                  u16* __restrict__ wouth) {
  const int e = blockIdx.x * 256 + threadIdx.x;
  if (e < NOUT * NN) wouth[e] = f2bf(Wout[e]);
}

// ---------------- K1 (MFMA): jx[t][b][n] = sum_k x[b][t][k] * Win[n][k] ----
__global__ __launch_bounds__(256) void k_in(const float* __restrict__ x,
                                            const u16* __restrict__ winh,
                                            u16* __restrict__ jx) {
  const int t = blockIdx.x;
  const int tid = threadIdx.x;
  const int wv = tid >> 6, lane = tid & 63;
  __shared__ u16 Xh[NB][136];
  __shared__ u16 Xl[NB][136];
  {
    const int b = tid >> 3, k0 = (tid & 7) * 16;
    const float* xp = x + ((size_t)b * NT + t) * NIN + k0;
    u16 hb[16], lb[16];
#pragma unroll
    for (int j = 0; j < 16; ++j) split_hl(xp[j], hb[j], lb[j]);
    *(uint4*)&Xh[b][k0]     = *(uint4*)&hb[0];
    *(uint4*)&Xh[b][k0 + 8] = *(uint4*)&hb[8];
    *(uint4*)&Xl[b][k0]     = *(uint4*)&lb[0];
    *(uint4*)&Xl[b][k0 + 8] = *(uint4*)&lb[8];
  }
  __syncthreads();

  const int r15 = lane & 15, kg = lane >> 4;
  const int n0 = 128 * wv;
  f32x4 acc[2][8];
#pragma unroll
  for (int mt = 0; mt < 2; ++mt)
#pragma unroll
    for (int nt = 0; nt < 8; ++nt) acc[mt][nt] = (f32x4){0.f, 0.f, 0.f, 0.f};

#pragma unroll
  for (int kt = 0; kt < 4; ++kt) {
    const int ko = 32 * kt + 8 * kg;
    const bf16x8 ah0 = *(const bf16x8*)&Xh[r15][ko];
    const bf16x8 ah1 = *(const bf16x8*)&Xh[16 + r15][ko];
    const bf16x8 al0 = *(const bf16x8*)&Xl[r15][ko];
    const bf16x8 al1 = *(const bf16x8*)&Xl[16 + r15][ko];
#pragma unroll
    for (int nt = 0; nt < 8; ++nt) {
      const int n = n0 + 16 * nt + r15;
      const bf16x8 bh = *(const bf16x8*)(winh + (size_t)n * NIN + ko);
      acc[0][nt] = __builtin_amdgcn_mfma_f32_16x16x32_bf16(ah0, bh, acc[0][nt], 0, 0, 0);
      acc[1][nt] = __builtin_amdgcn_mfma_f32_16x16x32_bf16(ah1, bh, acc[1][nt], 0, 0, 0);
      acc[0][nt] = __builtin_amdgcn_mfma_f32_16x16x32_bf16(al0, bh, acc[0][nt], 0, 0, 0);
      acc[1][nt] = __builtin_amdgcn_mfma_f32_16x16x32_bf16(al1, bh, acc[1][nt], 0, 0, 0);
    }
  }
#pragma unroll
  for (int mt = 0; mt < 2; ++mt)
#pragma unroll
    for (int nt = 0; nt < 8; ++nt) {
      const int n = n0 + 16 * nt + r15;
#pragma unroll
      for (int r = 0; r < 4; ++r) {
        const int b = 16 * mt + 4 * kg + r;
        jx[((size_t)t * NB + b) * NN + n] = f2bf(acc[mt][nt][r]);
      }
    }
}

// ---------------- K2: sequential scan --------------------------------------
__global__ __launch_bounds__(256) void k_scan(const float* __restrict__ Wrec,
                                              const float* __restrict__ brec,
                                              const u16* __restrict__ jx,
                                              u32* Hex,             // [2][NB][NN] 4B atoms
                                              u16* __restrict__ Hh) // [NT][NB][NN]
{
  const int wg = blockIdx.x;
  const int g = wg & 7, i = wg >> 3;
  const int tid = threadIdx.x;
  const int wv = tid >> 6, lane = tid & 63;

  // stride 528 u16 = 264 dw == 8 (mod 32): B-frag ds_read_b128 2-way -> free (m136)
  __shared__ u16 SHhi[2][4][528];
  __shared__ u16 SHlo[2][4][528];
  __shared__ float Pj[2][4][64];

  const int r15 = lane & 15, kg = lane >> 4;
  const int t64 = tid & 63;
  const float brv = brec[64 * i + t64];

  // resident A-frags: row = lane&15, k = 8*kg + j (contig-8)
  const int arow = 64 * i + 16 * wv + r15;
  bf16x8 afrag[16];
#pragma unroll
  for (int kt = 0; kt < 16; ++kt) {
    const float* wp = Wrec + (size_t)arow * NN + 32 * kt + 8 * kg;
    bf16x8 a;
#pragma unroll
    for (int j = 0; j < 8; ++j) a[j] = (__bf16)wp[j];
    afrag[kt] = a;
  }

  const int sc = wv;                 // staged chain (== wave)
  const int cc = r15;                // D col = chain (valid < 4)
  const int rb = 16 * wv + 4 * kg;   // D row base within WG slice
  const int gch = 4 * g + cc;
  const int ro = 64 * i + rb;        // global rows ro..ro+3 (ro%4==0)
  const bool ownrow = ((t64 >> 3) == i);  // polled rows are own WG's rows

  char* HexB_ = (char*)Hex;
  // consumer: rows 8*t64..+7 of chain sc -> 32B contiguous
  const char* cb = HexB_ + ((size_t)(4 * g + sc) * NN + 8 * t64) * 4;
  // producer: rows ro..ro+3 of chain gch -> one 16B line
  char* pb = HexB_ + ((size_t)gch * NN + ro) * 4;

  const char* jp = (const char*)jx + ((size_t)(NB + 4 * g + sc) * NN + 64 * i + t64) * 2;
  u16* hb = Hh + (size_t)gch * NN + ro;

  const float jxv0 = bf2f(jx[(size_t)(4 * g + sc) * NN + 64 * i + t64]);
  u32 jxu = 0;

  for (int s = 0; s < NT; ++s) {
    const int slot = s & 1;
    if (s > 0) {
      // sleep 3 (~192cy): first MALL sample at ~642cy, just past peer-commit
      asm volatile("s_sleep 3" :::);
      const char* cbs = cb + (slot ? PAR : 0);
      const u32 want = (u32)s & 7u;
      u32x4 A0 = ld_dev16(cbs);
      u32x4 A1 = ld_dev16(cbs + 16);
      asm volatile("s_waitcnt vmcnt(0)" ::: "memory");  // also drains jx + acks
      __builtin_amdgcn_sched_barrier(0);
      bool ok = ownrow | tags2(A0, A1, want);
      int guard = 1 << 16;                               // anti-hang only
      while (!__all(ok) && --guard) {
        A0 = ld_dev16(cbs);
        A1 = ld_dev16(cbs + 16);
        asm volatile("s_waitcnt vmcnt(0)" ::: "memory");
        __builtin_amdgcn_sched_barrier(0);
        ok = ownrow | tags2(A0, A1, want);
      }
      if (!ownrow) {
        // unpack: atom = [hi16 | lo13 | tag3]; rows ascend A0.x..A1.w
        const u32x4 hw = {(A0.x >> 16) | (A0.y & 0xffff0000u),
                          (A0.z >> 16) | (A0.w & 0xffff0000u),
                          (A1.x >> 16) | (A1.y & 0xffff0000u),
                          (A1.z >> 16) | (A1.w & 0xffff0000u)};
        const u32x4 lw = {(A0.x & 0xfff8u) | ((A0.y & 0xfff8u) << 16),
                          (A0.z & 0xfff8u) | ((A0.w & 0xfff8u) << 16),
                          (A1.x & 0xfff8u) | ((A1.y & 0xfff8u) << 16),
                          (A1.z & 0xfff8u) | ((A1.w & 0xfff8u) << 16)};
        *(u32x4*)&SHhi[slot][sc][8 * t64] = hw;
        *(u32x4*)&SHlo[slot][sc][8 * t64] = lw;
      }
      Pj[slot][sc][t64] = __uint_as_float(jxu << 16) + brv;
    } else {
      Pj[0][sc][t64] = jxv0 + brv;
    }

    // single barrier per step: drains only LDS writes (globals are vmcnt-only)
    asm volatile("s_waitcnt lgkmcnt(0)" ::: "memory");
    __builtin_amdgcn_s_barrier();
    __builtin_amdgcn_sched_barrier(0);

    // 4 independent MFMA chains: hi/lo x K-halves (breaks dependent latency)
    f32x4 ah0 = {0.f, 0.f, 0.f, 0.f}, ah1 = {0.f, 0.f, 0.f, 0.f};
    f32x4 al0 = {0.f, 0.f, 0.f, 0.f}, al1 = {0.f, 0.f, 0.f, 0.f};
    if (s > 0) {
      const int c4 = cc & 3;
#pragma unroll
      for (int kt = 0; kt < 8; ++kt) {
        const int ko  = 32 * kt + 8 * kg;
        const int ko2 = 32 * (kt + 8) + 8 * kg;
        const bf16x8 bh0 = *(const bf16x8*)&SHhi[slot][c4][ko];
        const bf16x8 bh1 = *(const bf16x8*)&SHhi[slot][c4][ko2];
        const bf16x8 bl0 = *(const bf16x8*)&SHlo[slot][c4][ko];
        const bf16x8 bl1 = *(const bf16x8*)&SHlo[slot][c4][ko2];
        ah0 = __builtin_amdgcn_mfma_f32_16x16x32_bf16(afrag[kt],     bh0, ah0, 0, 0, 0);
        ah1 = __builtin_amdgcn_mfma_f32_16x16x32_bf16(afrag[kt + 8], bh1, ah1, 0, 0, 0);
        al0 = __builtin_amdgcn_mfma_f32_16x16x32_bf16(afrag[kt],     bl0, al0, 0, 0, 0);
        al1 = __builtin_amdgcn_mfma_f32_16x16x32_bf16(afrag[kt + 8], bl1, al1, 0, 0, 0);
      }
    }
    const f32x4 acc = (ah0 + ah1) + (al0 + al1);

    // epilogue: publish FIRST, self-stage own rows, then Hh, then jx prefetch
    const int nsl = (s + 1) & 1;
    if (cc < 4) {
      const u32 tg = (u32)(s + 1) & 7u;
      u32 atom[4];
      u16 hp[4], lp[4];
#pragma unroll
      for (int r = 0; r < 4; ++r) {
        const float pre = acc[r] + Pj[slot][cc][rb + r];
        const float h = fast_tanh(pre);
        const u32 uh = __float_as_uint(h);
        lp[r] = (u16)(f2bf(h - __uint_as_float(uh & 0xffff0000u)) & 0xfff8u);
        hp[r] = (u16)(uh >> 16);
        atom[r] = (uh & 0xffff0000u) | (u32)lp[r] | tg;
      }
      st_dev16(pb + (nsl ? PAR : 0), (u32x4){atom[0], atom[1], atom[2], atom[3]});
      // self-stage own rows into next-slot LDS (never polled; same lo13 values)
      uint2 hw2, lw2;
      hw2.x = (u32)hp[0] | ((u32)hp[1] << 16);
      hw2.y = (u32)hp[2] | ((u32)hp[3] << 16);
      lw2.x = (u32)lp[0] | ((u32)lp[1] << 16);
      lw2.y = (u32)lp[2] | ((u32)lp[3] << 16);
      *(uint2*)&SHhi[nsl][cc][ro] = hw2;
      *(uint2*)&SHlo[nsl][cc][ro] = lw2;
      *(uint2*)hb = hw2;
    }
    hb += NBNN;

    // jx prefetch for next step (different address; no poll hazard)
    if (s + 1 < NT) {
      ld_u16a(jxu, jp);
      jp += 2 * NBNN;
    }
  }
}

// ---------------- K3 (MFMA): out[b][t][o] = sum_n Hh[t][b][n]*Wout[o][n] + bout[o]
__global__ __launch_bounds__(256) void k_out(const u16* __restrict__ Hh,
                                             const u16* __restrict__ wouth,
                                             const float* __restrict__ bout,
                                             float* __restrict__ out) {
  const int t = blockIdx.x;
  const int tid = threadIdx.x;
  const int wv = tid >> 6, lane = tid & 63;
  __shared__ u16 Ah[NB][528];
  {
    const int b = tid >> 3, k0 = (tid & 7) * 64;
    const u16* hp = Hh + ((size_t)t * NB + b) * NN + k0;
#pragma unroll
    for (int j = 0; j < 8; ++j)
      *(uint4*)&Ah[b][k0 + 8 * j] = *(const uint4*)(hp + 8 * j);
  }
  __syncthreads();

  const int r15 = lane & 15, kg = lane >> 4;
  const int o = 16 * wv + r15;
  f32x4 acc[2] = {{0.f, 0.f, 0.f, 0.f}, {0.f, 0.f, 0.f, 0.f}};
#pragma unroll
  for (int kt = 0; kt < 16; ++kt) {
    const int ko = 32 * kt + 8 * kg;
    const bf16x8 b0 = *(const bf16x8*)(wouth + (size_t)o * NN + ko);
    const bf16x8 a0 = *(const bf16x8*)&Ah[r15][ko];
    const bf16x8 a1 = *(const bf16x8*)&Ah[16 + r15][ko];
    acc[0] = __builtin_amdgcn_mfma_f32_16x16x32_bf16(a0, b0, acc[0], 0, 0, 0);
    acc[1] = __builtin_amdgcn_mfma_f32_16x16x32_bf16(a1, b0, acc[1], 0, 0, 0);
  }
  const float bo = bout[o];
#pragma unroll
  for (int mt = 0; mt < 2; ++mt)
#pragma unroll
    for (int r = 0; r < 4; ++r) {
      const int b = 16 * mt + 4 * kg + r;
      out[((size_t)b * NT + t) * NOUT + o] = acc[mt][r] + bo;
    }
}

// ---------------- launch ----------------------------------------------------
// ws: [0, 65,536,000)             jx bf16 [NT][NB][NN]  (post-scan: wouth @ +0)
//     [65,536,000, 131,072,000)   Hh bf16 [NT][NB][NN]  (pre-scan: winh @ +0)
//     [131,072,000, 131,203,072)  Hex u32 [2][NB][NN]   (4B self-tagged atoms)
extern "C" void kernel_launch(void* const* d_in, const int* in_sizes, int n_in,
                              void* d_out, int out_size, void* d_ws, size_t ws_size,
                              hipStream_t stream) {
  (void)in_sizes; (void)n_in; (void)out_size;
  const float* x    = (const float*)d_in[0];
  const float* Wrec = (const float*)d_in[1];
  const float* brec = (const float*)d_in[2];
  const float* Win  = (const float*)d_in[3];
  const float* Wout = (const float*)d_in[4];
  const float* bout = (const float*)d_in[5];
  float* out = (float*)d_out;

  if (ws_size < 131203072ULL) return;  // visible failure beacon

  char* ws = (char*)d_ws;
  u16* jx    = (u16*)ws;
  u16* Hh    = (u16*)(ws + 65536000);
  u32* Hex   = (u32*)(ws + 131072000);
  u16* winh  = (u16*)(ws + 65536000);  // overlays Hh (dead until k_scan)
  u16* wouth = (u16*)ws;               // overlays jx (dead after k_scan)

  hipMemsetAsync(Hex, 0, 2 * PAR, stream);   // kill poison/cross-launch tag aliases
  k_prep_in<<<dim3((NN * NIN + 255) / 256), dim3(256), 0, stream>>>(Win, winh);
  k_in<<<dim3(NT), dim3(256), 0, stream>>>(x, winh, jx);
  k_scan<<<dim3(64), dim3(256), 0, stream>>>(Wrec, brec, jx, Hex, Hh);
  k_prep_out<<<dim3((NOUT * NN + 255) / 256), dim3(256), 0, stream>>>(Wout, wouth);
  k_out<<<dim3(NT), dim3(256), 0, stream>>>(Hh, wouth, bout, out);
}

// Round 17
// 2605.741 us; speedup vs baseline: 1.6356x; 1.2614x over previous
//
#include <hip/hip_runtime.h>
#include <hip/hip_bf16.h>
#include <cstdint>

// RateModel: h_{s+1} = tanh(W_rec h_s + b_rec + W_in x_s); out = W_out h + b_out
// B=32, Nt=2000 (sequential), N=512, N_in=128, N_out=64.
//
// k_scan R17 = R13/R16 structure (proven 3247/3287us) with the LO-RESIDUAL
// PASS DROPPED: h enters the recurrence as bf16-hi only. Halves the serial
// compute block: 16 MFMAs (was 32), 16 ds_read_b128 (was 32), one staging
// write (was two), no lo unpack. Precision: bf16 quantization noise
// equilibrates under the contractive tanh Jacobian (radius ~0.5-0.8) at
// ~0.005-0.01 RMS -> predicted absmax ~0.10-0.15 vs threshold 0.1875.
// R14/R15/R16 falsified: longer delay, divergent retry, lower fan-in, and
// shorter sleep. Sleep stays 5 (producer publish and consumer step-top shift
// together when compute shrinks -> relative timing unchanged).
// Protocol (R4/R11/R13-proven): 4B atoms [hi16 | 0 | tag3], tag=step&7,
// sc0 sc1 (MALL; correct for ANY WG placement); skew<=1 => stale tag differs
// by 2 mod 8 => never false-validates; line-atomic tag check (R16-validated:
// 16B store = one MALL transaction); Hex memsetAsync(0) per launch. Polls
// STRICTLY issue->vmcnt(0)->check (R10 MSHR-merge livelock; R12 regalloc
// hazard). Deterministic, replay-safe.

#define NB   32
#define NT   2000
#define NIN  128
#define NN   512
#define NOUT 64
#define NBNN (NB * NN)
#define PAR  65536            // bytes per parity slot (u32[32][512])

typedef unsigned short u16;
typedef unsigned int   u32;
typedef unsigned long long u64;
typedef __bf16 bf16x8 __attribute__((ext_vector_type(8)));
typedef float  f32x4  __attribute__((ext_vector_type(4)));
typedef u32    u32x4  __attribute__((ext_vector_type(4)));

static __device__ __forceinline__ u16 f2bf(float f) {
  return __builtin_bit_cast(u16, (__bf16)f);   // RNE
}
static __device__ __forceinline__ float bf2f(u16 u) {
  return (float)__builtin_bit_cast(__bf16, u);
}
static __device__ __forceinline__ void split_hl(float f, u16& hi, u16& lo) {
  const u32 u = __float_as_uint(f);
  hi = (u16)(u >> 16);                                   // truncated bf16
  lo = f2bf(f - __uint_as_float(u & 0xffff0000u));       // residual
}
static __device__ __forceinline__ float fast_tanh(float x) {
  const float xc = fminf(fmaxf(x, -12.f), 12.f);
  const float t = __builtin_amdgcn_exp2f(xc * 2.8853900817779268f); // 2*log2(e)
  return (t - 1.f) * __builtin_amdgcn_rcpf(t + 1.f);
}

// device-scope (MALL) 16B ops; vmcnt-only, invisible to compiler's wait model
static __device__ __forceinline__ u32x4 ld_dev16(const void* p) {
  u32x4 r;
  asm volatile("global_load_dwordx4 %0, %1, off sc0 sc1" : "=v"(r) : "v"(p) : "memory");
  return r;
}
static __device__ __forceinline__ void st_dev16(void* p, u32x4 v) {
  asm volatile("global_store_dwordx4 %0, %1, off sc0 sc1" :: "v"(p), "v"(v) : "memory");
}
static __device__ __forceinline__ void ld_u16a(u32& d, const void* p) {
  asm volatile("global_load_ushort %0, %1, off" : "=v"(d) : "v"(p) : "memory");
}
// line-atomic: one tag per 16B line suffices (16B store = 1 MALL transaction)
static __device__ __forceinline__ bool tags2(u32x4 a, u32x4 b, u32 want) {
  return ((a.x & 7u) == want) & ((b.x & 7u) == want);
}

// ---------------- prep: bf16 weight tables --------------------------------
__global__ __launch_bounds__(256) void k_prep_in(const float* __restrict__ Win,
                                                 u16* __restrict__ winh) {
  const int e = blockIdx.x * 256 + threadIdx.x;
  if (e < NN * NIN) winh[e] = f2bf(Win[e]);
}
__global__ __launch_bounds__(256) void k_prep_out(const float* __restrict__ Wout,
                                                  u16* __restrict__ wouth) {
  const int e = blockIdx.x * 256 + threadIdx.x;
  if (e < NOUT * NN) wouth[e] = f2bf(Wout[e]);
}

// ---------------- K1 (MFMA): jx[t][b][n] = sum_k x[b][t][k] * Win[n][k] ----
__global__ __launch_bounds__(256) void k_in(const float* __restrict__ x,
                                            const u16* __restrict__ winh,
                                            u16* __restrict__ jx) {
  const int t = blockIdx.x;
  const int tid = threadIdx.x;
  const int wv = tid >> 6, lane = tid & 63;
  __shared__ u16 Xh[NB][136];
  __shared__ u16 Xl[NB][136];
  {
    const int b = tid >> 3, k0 = (tid & 7) * 16;
    const float* xp = x + ((size_t)b * NT + t) * NIN + k0;
    u16 hb[16], lb[16];
#pragma unroll
    for (int j = 0; j < 16; ++j) split_hl(xp[j], hb[j], lb[j]);
    *(uint4*)&Xh[b][k0]     = *(uint4*)&hb[0];
    *(uint4*)&Xh[b][k0 + 8] = *(uint4*)&hb[8];
    *(uint4*)&Xl[b][k0]     = *(uint4*)&lb[0];
    *(uint4*)&Xl[b][k0 + 8] = *(uint4*)&lb[8];
  }
  __syncthreads();

  const int r15 = lane & 15, kg = lane >> 4;
  const int n0 = 128 * wv;
  f32x4 acc[2][8];
#pragma unroll
  for (int mt = 0; mt < 2; ++mt)
#pragma unroll
    for (int nt = 0; nt < 8; ++nt) acc[mt][nt] = (f32x4){0.f, 0.f, 0.f, 0.f};

#pragma unroll
  for (int kt = 0; kt < 4; ++kt) {
    const int ko = 32 * kt + 8 * kg;
    const bf16x8 ah0 = *(const bf16x8*)&Xh[r15][ko];
    const bf16x8 ah1 = *(const bf16x8*)&Xh[16 + r15][ko];
    const bf16x8 al0 = *(const bf16x8*)&Xl[r15][ko];
    const bf16x8 al1 = *(const bf16x8*)&Xl[16 + r15][ko];
#pragma unroll
    for (int nt = 0; nt < 8; ++nt) {
      const int n = n0 + 16 * nt + r15;
      const bf16x8 bh = *(const bf16x8*)(winh + (size_t)n * NIN + ko);
      acc[0][nt] = __builtin_amdgcn_mfma_f32_16x16x32_bf16(ah0, bh, acc[0][nt], 0, 0, 0);
      acc[1][nt] = __builtin_amdgcn_mfma_f32_16x16x32_bf16(ah1, bh, acc[1][nt], 0, 0, 0);
      acc[0][nt] = __builtin_amdgcn_mfma_f32_16x16x32_bf16(al0, bh, acc[0][nt], 0, 0, 0);
      acc[1][nt] = __builtin_amdgcn_mfma_f32_16x16x32_bf16(al1, bh, acc[1][nt], 0, 0, 0);
    }
  }
#pragma unroll
  for (int mt = 0; mt < 2; ++mt)
#pragma unroll
    for (int nt = 0; nt < 8; ++nt) {
      const int n = n0 + 16 * nt + r15;
#pragma unroll
      for (int r = 0; r < 4; ++r) {
        const int b = 16 * mt + 4 * kg + r;
        jx[((size_t)t * NB + b) * NN + n] = f2bf(acc[mt][nt][r]);
      }
    }
}

// ---------------- K2: sequential scan --------------------------------------
__global__ __launch_bounds__(256) void k_scan(const float* __restrict__ Wrec,
                                              const float* __restrict__ brec,
                                              const u16* __restrict__ jx,
                                              u32* Hex,             // [2][NB][NN] 4B atoms
                                              u16* __restrict__ Hh) // [NT][NB][NN]
{
  const int wg = blockIdx.x;
  const int g = wg & 7, i = wg >> 3;
  const int tid = threadIdx.x;
  const int wv = tid >> 6, lane = tid & 63;

  // stride 528 u16 = 264 dw == 8 (mod 32): B-frag ds_read_b128 2-way -> free (m136)
  __shared__ u16 SHhi[2][4][528];
  __shared__ float Pj[2][4][64];

  const int r15 = lane & 15, kg = lane >> 4;
  const int t64 = tid & 63;
  const float brv = brec[64 * i + t64];

  // resident A-frags: row = lane&15, k = 8*kg + j (contig-8)
  const int arow = 64 * i + 16 * wv + r15;
  bf16x8 afrag[16];
#pragma unroll
  for (int kt = 0; kt < 16; ++kt) {
    const float* wp = Wrec + (size_t)arow * NN + 32 * kt + 8 * kg;
    bf16x8 a;
#pragma unroll
    for (int j = 0; j < 8; ++j) a[j] = (__bf16)wp[j];
    afrag[kt] = a;
  }

  const int sc = wv;                 // staged chain (== wave)
  const int cc = r15;                // D col = chain (valid < 4)
  const int rb = 16 * wv + 4 * kg;   // D row base within WG slice
  const int gch = 4 * g + cc;
  const int ro = 64 * i + rb;        // global rows ro..ro+3 (ro%4==0)
  const bool ownrow = ((t64 >> 3) == i);  // polled rows are own WG's rows

  char* HexB_ = (char*)Hex;
  // consumer: rows 8*t64..+7 of chain sc -> 32B contiguous
  const char* cb = HexB_ + ((size_t)(4 * g + sc) * NN + 8 * t64) * 4;
  // producer: rows ro..ro+3 of chain gch -> one 16B line
  char* pb = HexB_ + ((size_t)gch * NN + ro) * 4;

  const char* jp = (const char*)jx + ((size_t)(NB + 4 * g + sc) * NN + 64 * i + t64) * 2;
  u16* hb = Hh + (size_t)gch * NN + ro;

  const float jxv0 = bf2f(jx[(size_t)(4 * g + sc) * NN + 64 * i + t64]);
  u32 jxu = 0;

  for (int s = 0; s < NT; ++s) {
    const int slot = s & 1;
    if (s > 0) {
      // R13-proven pacing: sleep 5 (~320cy), then strictly serialized rounds
      asm volatile("s_sleep 5" :::);
      const char* cbs = cb + (slot ? PAR : 0);
      const u32 want = (u32)s & 7u;
      u32x4 A0 = ld_dev16(cbs);
      u32x4 A1 = ld_dev16(cbs + 16);
      asm volatile("s_waitcnt vmcnt(0)" ::: "memory");  // also drains jx + acks
      __builtin_amdgcn_sched_barrier(0);
      bool ok = ownrow | tags2(A0, A1, want);
      int guard = 1 << 16;                               // anti-hang only
      while (!__all(ok) && --guard) {
        A0 = ld_dev16(cbs);
        A1 = ld_dev16(cbs + 16);
        asm volatile("s_waitcnt vmcnt(0)" ::: "memory");
        __builtin_amdgcn_sched_barrier(0);
        ok = ownrow | tags2(A0, A1, want);
      }
      if (!ownrow) {
        // unpack: atom = [hi16 | 0 | tag3]; rows ascend A0.x..A1.w (hi only)
        const u32x4 hw = {(A0.x >> 16) | (A0.y & 0xffff0000u),
                          (A0.z >> 16) | (A0.w & 0xffff0000u),
                          (A1.x >> 16) | (A1.y & 0xffff0000u),
                          (A1.z >> 16) | (A1.w & 0xffff0000u)};
        *(u32x4*)&SHhi[slot][sc][8 * t64] = hw;
      }
      Pj[slot][sc][t64] = __uint_as_float(jxu << 16) + brv;
    } else {
      Pj[0][sc][t64] = jxv0 + brv;
    }

    // single barrier per step: drains only LDS writes (globals are vmcnt-only)
    asm volatile("s_waitcnt lgkmcnt(0)" ::: "memory");
    __builtin_amdgcn_s_barrier();
    __builtin_amdgcn_sched_barrier(0);

    // 4 independent MFMA chains (K-quarters), hi-only
    f32x4 a0 = {0.f, 0.f, 0.f, 0.f}, a1 = {0.f, 0.f, 0.f, 0.f};
    f32x4 a2 = {0.f, 0.f, 0.f, 0.f}, a3 = {0.f, 0.f, 0.f, 0.f};
    if (s > 0) {
      const int c4 = cc & 3;
#pragma unroll
      for (int kt = 0; kt < 4; ++kt) {
        const int k0 = 32 * kt + 8 * kg;
        const bf16x8 b0 = *(const bf16x8*)&SHhi[slot][c4][k0];
        const bf16x8 b1 = *(const bf16x8*)&SHhi[slot][c4][k0 + 128];
        const bf16x8 b2 = *(const bf16x8*)&SHhi[slot][c4][k0 + 256];
        const bf16x8 b3 = *(const bf16x8*)&SHhi[slot][c4][k0 + 384];
        a0 = __builtin_amdgcn_mfma_f32_16x16x32_bf16(afrag[kt],      b0, a0, 0, 0, 0);
        a1 = __builtin_amdgcn_mfma_f32_16x16x32_bf16(afrag[kt + 4],  b1, a1, 0, 0, 0);
        a2 = __builtin_amdgcn_mfma_f32_16x16x32_bf16(afrag[kt + 8],  b2, a2, 0, 0, 0);
        a3 = __builtin_amdgcn_mfma_f32_16x16x32_bf16(afrag[kt + 12], b3, a3, 0, 0, 0);
      }
    }
    const f32x4 acc = (a0 + a1) + (a2 + a3);

    // epilogue: publish FIRST, self-stage own rows (hi), then Hh, jx prefetch
    const int nsl = (s + 1) & 1;
    if (cc < 4) {
      const u32 tg = (u32)(s + 1) & 7u;
      u32 atom[4];
      u16 hp[4];
#pragma unroll
      for (int r = 0; r < 4; ++r) {
        const float pre = acc[r] + Pj[slot][cc][rb + r];
        const float h = fast_tanh(pre);
        const u32 uh = __float_as_uint(h);
        hp[r] = (u16)(uh >> 16);
        atom[r] = (uh & 0xffff0000u) | tg;     // [hi16 | 0 | tag3]
      }
      st_dev16(pb + (nsl ? PAR : 0), (u32x4){atom[0], atom[1], atom[2], atom[3]});
      uint2 hw2;
      hw2.x = (u32)hp[0] | ((u32)hp[1] << 16);
      hw2.y = (u32)hp[2] | ((u32)hp[3] << 16);
      *(uint2*)&SHhi[nsl][cc][ro] = hw2;       // self-stage (never polled)
      *(uint2*)hb = hw2;
    }
    hb += NBNN;

    // jx prefetch for next step (different address; no poll hazard)
    if (s + 1 < NT) {
      ld_u16a(jxu, jp);
      jp += 2 * NBNN;
    }
  }
}

// ---------------- K3 (MFMA): out[b][t][o] = sum_n Hh[t][b][n]*Wout[o][n] + bout[o]
__global__ __launch_bounds__(256) void k_out(const u16* __restrict__ Hh,
                                             const u16* __restrict__ wouth,
                                             const float* __restrict__ bout,
                                             float* __restrict__ out) {
  const int t = blockIdx.x;
  const int tid = threadIdx.x;
  const int wv = tid >> 6, lane = tid & 63;
  __shared__ u16 Ah[NB][528];
  {
    const int b = tid >> 3, k0 = (tid & 7) * 64;
    const u16* hp = Hh + ((size_t)t * NB + b) * NN + k0;
#pragma unroll
    for (int j = 0; j < 8; ++j)
      *(uint4*)&Ah[b][k0 + 8 * j] = *(const uint4*)(hp + 8 * j);
  }
  __syncthreads();

  const int r15 = lane & 15, kg = lane >> 4;
  const int o = 16 * wv + r15;
  f32x4 acc[2] = {{0.f, 0.f, 0.f, 0.f}, {0.f, 0.f, 0.f, 0.f}};
#pragma unroll
  for (int kt = 0; kt < 16; ++kt) {
    const int ko = 32 * kt + 8 * kg;
    const bf16x8 b0 = *(const bf16x8*)(wouth + (size_t)o * NN + ko);
    const bf16x8 a0 = *(const bf16x8*)&Ah[r15][ko];
    const bf16x8 a1 = *(const bf16x8*)&Ah[16 + r15][ko];
    acc[0] = __builtin_amdgcn_mfma_f32_16x16x32_bf16(a0, b0, acc[0], 0, 0, 0);
    acc[1] = __builtin_amdgcn_mfma_f32_16x16x32_bf16(a1, b0, acc[1], 0, 0, 0);
  }
  const float bo = bout[o];
#pragma unroll
  for (int mt = 0; mt < 2; ++mt)
#pragma unroll
    for (int r = 0; r < 4; ++r) {
      const int b = 16 * mt + 4 * kg + r;
      out[((size_t)b * NT + t) * NOUT + o] = acc[mt][r] + bo;
    }
}

// ---------------- launch ----------------------------------------------------
// ws: [0, 65,536,000)             jx bf16 [NT][NB][NN]  (post-scan: wouth @ +0)
//     [65,536,000, 131,072,000)   Hh bf16 [NT][NB][NN]  (pre-scan: winh @ +0)
//     [131,072,000, 131,203,072)  Hex u32 [2][NB][NN]   (4B self-tagged atoms)
extern "C" void kernel_launch(void* const* d_in, const int* in_sizes, int n_in,
                              void* d_out, int out_size, void* d_ws, size_t ws_size,
                              hipStream_t stream) {
  (void)in_sizes; (void)n_in; (void)out_size;
  const float* x    = (const float*)d_in[0];
  const float* Wrec = (const float*)d_in[1];
  const float* brec = (const float*)d_in[2];
  const float* Win  = (const float*)d_in[3];
  const float* Wout = (const float*)d_in[4];
  const float* bout = (const float*)d_in[5];
  float* out = (float*)d_out;

  if (ws_size < 131203072ULL) return;  // visible failure beacon

  char* ws = (char*)d_ws;
  u16* jx    = (u16*)ws;
  u16* Hh    = (u16*)(ws + 65536000);
  u32* Hex   = (u32*)(ws + 131072000);
  u16* winh  = (u16*)(ws + 65536000);  // overlays Hh (dead until k_scan)
  u16* wouth = (u16*)ws;               // overlays jx (dead after k_scan)

  hipMemsetAsync(Hex, 0, 2 * PAR, stream);   // kill poison/cross-launch tag aliases
  k_prep_in<<<dim3((NN * NIN + 255) / 256), dim3(256), 0, stream>>>(Win, winh);
  k_in<<<dim3(NT), dim3(256), 0, stream>>>(x, winh, jx);
  k_scan<<<dim3(64), dim3(256), 0, stream>>>(Wrec, brec, jx, Hex, Hh);
  k_prep_out<<<dim3((NOUT * NN + 255) / 256), dim3(256), 0, stream>>>(Wout, wouth);
  k_out<<<dim3(NT), dim3(256), 0, stream>>>(Hh, wouth, bout, out);
}

// Round 18
// 2524.572 us; speedup vs baseline: 1.6882x; 1.0322x over previous
//
#include <hip/hip_runtime.h>
#include <hip/hip_bf16.h>
#include <cstdint>

// RateModel: h_{s+1} = tanh(W_rec h_s + b_rec + W_in x_s); out = W_out h + b_out
// B=32, Nt=2000 (sequential), N=512, N_in=128, N_out=64.
//
// k_scan R18 = R17 (proven: 2532us k_scan; hi-only bf16 recurrence) + ledger fix:
//  - DEFERRED Hh STORE: the history store (plain, HBM) is issued AFTER the
//    next step's poll loads, and the first tag-check waits vmcnt(1) instead of
//    vmcnt(0). R17's step-top vmcnt(0) FIFO-drained the epilogue's Hh store
//    ack (~600-900cy HBM) before the polls could be consumed. Ledger at check
//    (oldest->newest): [publish, jx, A0, A1, Hh'] -> vmcnt(1) retires the 4
//    oldest. Out-of-order store retirement worst case leaves a poll unretired
//    -> stale register -> tag check FAILS -> vmcnt(0) retry corrects it
//    (self-validating; never wrong, at most one extra round). All loop VMEM is
//    inline-asm so the ledger is exact. Final step's Hh stored after the loop.
//  - k_prep_out launched before k_scan (overlap; it only needs Wout).
// Protocol (R4/R11/R13/R17-proven): 4B atoms [hi16|0|tag3], tag=step&7,
// sc0 sc1 (MALL; any WG placement); skew<=1 => stale tag differs by 2 mod 8
// => never false-validates; line-atomic tag check; Hex memsetAsync(0) per
// launch. Polls strictly serialized per address (R10 MSHR-merge). No in-flight
// asm dests across control flow (R12). Deterministic, replay-safe.

#define NB   32
#define NT   2000
#define NIN  128
#define NN   512
#define NOUT 64
#define NBNN (NB * NN)
#define PAR  65536            // bytes per parity slot (u32[32][512])

typedef unsigned short u16;
typedef unsigned int   u32;
typedef unsigned long long u64;
typedef __bf16 bf16x8 __attribute__((ext_vector_type(8)));
typedef float  f32x4  __attribute__((ext_vector_type(4)));
typedef u32    u32x4  __attribute__((ext_vector_type(4)));

static __device__ __forceinline__ u16 f2bf(float f) {
  return __builtin_bit_cast(u16, (__bf16)f);   // RNE
}
static __device__ __forceinline__ float bf2f(u16 u) {
  return (float)__builtin_bit_cast(__bf16, u);
}
static __device__ __forceinline__ void split_hl(float f, u16& hi, u16& lo) {
  const u32 u = __float_as_uint(f);
  hi = (u16)(u >> 16);                                   // truncated bf16
  lo = f2bf(f - __uint_as_float(u & 0xffff0000u));       // residual
}
static __device__ __forceinline__ float fast_tanh(float x) {
  const float xc = fminf(fmaxf(x, -12.f), 12.f);
  const float t = __builtin_amdgcn_exp2f(xc * 2.8853900817779268f); // 2*log2(e)
  return (t - 1.f) * __builtin_amdgcn_rcpf(t + 1.f);
}

// device-scope (MALL) 16B ops; vmcnt-only, invisible to compiler's wait model
static __device__ __forceinline__ u32x4 ld_dev16(const void* p) {
  u32x4 r;
  asm volatile("global_load_dwordx4 %0, %1, off sc0 sc1" : "=v"(r) : "v"(p) : "memory");
  return r;
}
static __device__ __forceinline__ void st_dev16(void* p, u32x4 v) {
  asm volatile("global_store_dwordx4 %0, %1, off sc0 sc1" :: "v"(p), "v"(v) : "memory");
}
static __device__ __forceinline__ void st_plain8(void* p, u64 v) {
  asm volatile("global_store_dwordx2 %0, %1, off" :: "v"(p), "v"(v) : "memory");
}
static __device__ __forceinline__ void ld_u16a(u32& d, const void* p) {
  asm volatile("global_load_ushort %0, %1, off" : "=v"(d) : "v"(p) : "memory");
}
// line-atomic: one tag per 16B line suffices (16B store = 1 MALL transaction)
static __device__ __forceinline__ bool tags2(u32x4 a, u32x4 b, u32 want) {
  return ((a.x & 7u) == want) & ((b.x & 7u) == want);
}

// ---------------- prep: bf16 weight tables --------------------------------
__global__ __launch_bounds__(256) void k_prep_in(const float* __restrict__ Win,
                                                 u16* __restrict__ winh) {
  const int e = blockIdx.x * 256 + threadIdx.x;
  if (e < NN * NIN) winh[e] = f2bf(Win[e]);
}
__global__ __launch_bounds__(256) void k_prep_out(const float* __restrict__ Wout,
                                                  u16* __restrict__ wouth) {
  const int e = blockIdx.x * 256 + threadIdx.x;
  if (e < NOUT * NN) wouth[e] = f2bf(Wout[e]);
}

// ---------------- K1 (MFMA): jx[t][b][n] = sum_k x[b][t][k] * Win[n][k] ----
__global__ __launch_bounds__(256) void k_in(const float* __restrict__ x,
                                            const u16* __restrict__ winh,
                                            u16* __restrict__ jx) {
  const int t = blockIdx.x;
  const int tid = threadIdx.x;
  const int wv = tid >> 6, lane = tid & 63;
  __shared__ u16 Xh[NB][136];
  __shared__ u16 Xl[NB][136];
  {
    const int b = tid >> 3, k0 = (tid & 7) * 16;
    const float* xp = x + ((size_t)b * NT + t) * NIN + k0;
    u16 hb[16], lb[16];
#pragma unroll
    for (int j = 0; j < 16; ++j) split_hl(xp[j], hb[j], lb[j]);
    *(uint4*)&Xh[b][k0]     = *(uint4*)&hb[0];
    *(uint4*)&Xh[b][k0 + 8] = *(uint4*)&hb[8];
    *(uint4*)&Xl[b][k0]     = *(uint4*)&lb[0];
    *(uint4*)&Xl[b][k0 + 8] = *(uint4*)&lb[8];
  }
  __syncthreads();

  const int r15 = lane & 15, kg = lane >> 4;
  const int n0 = 128 * wv;
  f32x4 acc[2][8];
#pragma unroll
  for (int mt = 0; mt < 2; ++mt)
#pragma unroll
    for (int nt = 0; nt < 8; ++nt) acc[mt][nt] = (f32x4){0.f, 0.f, 0.f, 0.f};

#pragma unroll
  for (int kt = 0; kt < 4; ++kt) {
    const int ko = 32 * kt + 8 * kg;
    const bf16x8 ah0 = *(const bf16x8*)&Xh[r15][ko];
    const bf16x8 ah1 = *(const bf16x8*)&Xh[16 + r15][ko];
    const bf16x8 al0 = *(const bf16x8*)&Xl[r15][ko];
    const bf16x8 al1 = *(const bf16x8*)&Xl[16 + r15][ko];
#pragma unroll
    for (int nt = 0; nt < 8; ++nt) {
      const int n = n0 + 16 * nt + r15;
      const bf16x8 bh = *(const bf16x8*)(winh + (size_t)n * NIN + ko);
      acc[0][nt] = __builtin_amdgcn_mfma_f32_16x16x32_bf16(ah0, bh, acc[0][nt], 0, 0, 0);
      acc[1][nt] = __builtin_amdgcn_mfma_f32_16x16x32_bf16(ah1, bh, acc[1][nt], 0, 0, 0);
      acc[0][nt] = __builtin_amdgcn_mfma_f32_16x16x32_bf16(al0, bh, acc[0][nt], 0, 0, 0);
      acc[1][nt] = __builtin_amdgcn_mfma_f32_16x16x32_bf16(al1, bh, acc[1][nt], 0, 0, 0);
    }
  }
#pragma unroll
  for (int mt = 0; mt < 2; ++mt)
#pragma unroll
    for (int nt = 0; nt < 8; ++nt) {
      const int n = n0 + 16 * nt + r15;
#pragma unroll
      for (int r = 0; r < 4; ++r) {
        const int b = 16 * mt + 4 * kg + r;
        jx[((size_t)t * NB + b) * NN + n] = f2bf(acc[mt][nt][r]);
      }
    }
}

// ---------------- K2: sequential scan --------------------------------------
__global__ __launch_bounds__(256) void k_scan(const float* __restrict__ Wrec,
                                              const float* __restrict__ brec,
                                              const u16* __restrict__ jx,
                                              u32* Hex,             // [2][NB][NN] 4B atoms
                                              u16* __restrict__ Hh) // [NT][NB][NN]
{
  const int wg = blockIdx.x;
  const int g = wg & 7, i = wg >> 3;
  const int tid = threadIdx.x;
  const int wv = tid >> 6, lane = tid & 63;

  // stride 528 u16 = 264 dw == 8 (mod 32): B-frag ds_read_b128 2-way -> free (m136)
  __shared__ u16 SHhi[2][4][528];
  __shared__ float Pj[2][4][64];

  const int r15 = lane & 15, kg = lane >> 4;
  const int t64 = tid & 63;
  const float brv = brec[64 * i + t64];

  // resident A-frags: row = lane&15, k = 8*kg + j (contig-8)
  const int arow = 64 * i + 16 * wv + r15;
  bf16x8 afrag[16];
#pragma unroll
  for (int kt = 0; kt < 16; ++kt) {
    const float* wp = Wrec + (size_t)arow * NN + 32 * kt + 8 * kg;
    bf16x8 a;
#pragma unroll
    for (int j = 0; j < 8; ++j) a[j] = (__bf16)wp[j];
    afrag[kt] = a;
  }

  const int sc = wv;                 // staged chain (== wave)
  const int cc = r15;                // D col = chain (valid < 4)
  const int rb = 16 * wv + 4 * kg;   // D row base within WG slice
  const int gch = 4 * g + cc;
  const int ro = 64 * i + rb;        // global rows ro..ro+3 (ro%4==0)
  const bool ownrow = ((t64 >> 3) == i);  // polled rows are own WG's rows

  char* HexB_ = (char*)Hex;
  // consumer: rows 8*t64..+7 of chain sc -> 32B contiguous
  const char* cb = HexB_ + ((size_t)(4 * g + sc) * NN + 8 * t64) * 4;
  // producer: rows ro..ro+3 of chain gch -> one 16B line
  char* pb = HexB_ + ((size_t)gch * NN + ro) * 4;

  const char* jp = (const char*)jx + ((size_t)(NB + 4 * g + sc) * NN + 64 * i + t64) * 2;
  u16* hb = Hh + (size_t)gch * NN + ro;

  const float jxv0 = bf2f(jx[(size_t)(4 * g + sc) * NN + 64 * i + t64]);
  u32 jxu = 0;
  u64 hprev = 0;                      // deferred Hh payload (computed value)
  u16* hbprev = hb;                   // deferred Hh address

  for (int s = 0; s < NT; ++s) {
    const int slot = s & 1;
    if (s > 0) {
      // R13-proven pacing, then polls; deferred Hh store goes AFTER the polls
      asm volatile("s_sleep 5" :::);
      const char* cbs = cb + (slot ? PAR : 0);
      const u32 want = (u32)s & 7u;
      u32x4 A0 = ld_dev16(cbs);
      u32x4 A1 = ld_dev16(cbs + 16);
      if (cc < 4) st_plain8(hbprev, hprev);             // prev step's history
      // ledger (oldest->newest): [publish, jx, A0, A1, Hh] -> retire 4 oldest
      asm volatile("s_waitcnt vmcnt(1)" ::: "memory");
      __builtin_amdgcn_sched_barrier(0);
      Pj[slot][sc][t64] = __uint_as_float(jxu << 16) + brv;  // jx retired
      bool ok = ownrow | tags2(A0, A1, want);
      int guard = 1 << 16;                               // anti-hang only
      while (!__all(ok) && --guard) {
        A0 = ld_dev16(cbs);
        A1 = ld_dev16(cbs + 16);
        asm volatile("s_waitcnt vmcnt(0)" ::: "memory"); // retries drain all
        __builtin_amdgcn_sched_barrier(0);
        ok = ownrow | tags2(A0, A1, want);
      }
      if (!ownrow) {
        // unpack: atom = [hi16 | 0 | tag3]; rows ascend A0.x..A1.w (hi only)
        const u32x4 hw = {(A0.x >> 16) | (A0.y & 0xffff0000u),
                          (A0.z >> 16) | (A0.w & 0xffff0000u),
                          (A1.x >> 16) | (A1.y & 0xffff0000u),
                          (A1.z >> 16) | (A1.w & 0xffff0000u)};
        *(u32x4*)&SHhi[slot][sc][8 * t64] = hw;
      }
    } else {
      Pj[0][sc][t64] = jxv0 + brv;
    }

    // single barrier per step: drains only LDS writes (globals are vmcnt-only)
    asm volatile("s_waitcnt lgkmcnt(0)" ::: "memory");
    __builtin_amdgcn_s_barrier();
    __builtin_amdgcn_sched_barrier(0);

    // 4 independent MFMA chains (K-quarters), hi-only
    f32x4 a0 = {0.f, 0.f, 0.f, 0.f}, a1 = {0.f, 0.f, 0.f, 0.f};
    f32x4 a2 = {0.f, 0.f, 0.f, 0.f}, a3 = {0.f, 0.f, 0.f, 0.f};
    if (s > 0) {
      const int c4 = cc & 3;
#pragma unroll
      for (int kt = 0; kt < 4; ++kt) {
        const int k0 = 32 * kt + 8 * kg;
        const bf16x8 b0 = *(const bf16x8*)&SHhi[slot][c4][k0];
        const bf16x8 b1 = *(const bf16x8*)&SHhi[slot][c4][k0 + 128];
        const bf16x8 b2 = *(const bf16x8*)&SHhi[slot][c4][k0 + 256];
        const bf16x8 b3 = *(const bf16x8*)&SHhi[slot][c4][k0 + 384];
        a0 = __builtin_amdgcn_mfma_f32_16x16x32_bf16(afrag[kt],      b0, a0, 0, 0, 0);
        a1 = __builtin_amdgcn_mfma_f32_16x16x32_bf16(afrag[kt + 4],  b1, a1, 0, 0, 0);
        a2 = __builtin_amdgcn_mfma_f32_16x16x32_bf16(afrag[kt + 8],  b2, a2, 0, 0, 0);
        a3 = __builtin_amdgcn_mfma_f32_16x16x32_bf16(afrag[kt + 12], b3, a3, 0, 0, 0);
      }
    }
    const f32x4 acc = (a0 + a1) + (a2 + a3);

    // epilogue: publish FIRST (peers' critical path), self-stage own rows,
    // DEFER the Hh store to next step (after its polls), then jx prefetch
    const int nsl = (s + 1) & 1;
    if (cc < 4) {
      const u32 tg = (u32)(s + 1) & 7u;
      u32 atom[4];
      u16 hp[4];
#pragma unroll
      for (int r = 0; r < 4; ++r) {
        const float pre = acc[r] + Pj[slot][cc][rb + r];
        const float h = fast_tanh(pre);
        const u32 uh = __float_as_uint(h);
        hp[r] = (u16)(uh >> 16);
        atom[r] = (uh & 0xffff0000u) | tg;     // [hi16 | 0 | tag3]
      }
      st_dev16(pb + (nsl ? PAR : 0), (u32x4){atom[0], atom[1], atom[2], atom[3]});
      uint2 hw2;
      hw2.x = (u32)hp[0] | ((u32)hp[1] << 16);
      hw2.y = (u32)hp[2] | ((u32)hp[3] << 16);
      *(uint2*)&SHhi[nsl][cc][ro] = hw2;       // self-stage (never polled)
      hprev = (u64)hw2.x | ((u64)hw2.y << 32); // defer history store
      hbprev = hb;
    }
    hb += NBNN;

    // jx prefetch for next step (different address; no poll hazard)
    if (s + 1 < NT) {
      ld_u16a(jxu, jp);
      jp += 2 * NBNN;
    }
  }
  // final step's deferred history store
  if (cc < 4) st_plain8(hbprev, hprev);
}

// ---------------- K3 (MFMA): out[b][t][o] = sum_n Hh[t][b][n]*Wout[o][n] + bout[o]
__global__ __launch_bounds__(256) void k_out(const u16* __restrict__ Hh,
                                             const u16* __restrict__ wouth,
                                             const float* __restrict__ bout,
                                             float* __restrict__ out) {
  const int t = blockIdx.x;
  const int tid = threadIdx.x;
  const int wv = tid >> 6, lane = tid & 63;
  __shared__ u16 Ah[NB][528];
  {
    const int b = tid >> 3, k0 = (tid & 7) * 64;
    const u16* hp = Hh + ((size_t)t * NB + b) * NN + k0;
#pragma unroll
    for (int j = 0; j < 8; ++j)
      *(uint4*)&Ah[b][k0 + 8 * j] = *(const uint4*)(hp + 8 * j);
  }
  __syncthreads();

  const int r15 = lane & 15, kg = lane >> 4;
  const int o = 16 * wv + r15;
  f32x4 acc[2] = {{0.f, 0.f, 0.f, 0.f}, {0.f, 0.f, 0.f, 0.f}};
#pragma unroll
  for (int kt = 0; kt < 16; ++kt) {
    const int ko = 32 * kt + 8 * kg;
    const bf16x8 b0 = *(const bf16x8*)(wouth + (size_t)o * NN + ko);
    const bf16x8 a0 = *(const bf16x8*)&Ah[r15][ko];
    const bf16x8 a1 = *(const bf16x8*)&Ah[16 + r15][ko];
    acc[0] = __builtin_amdgcn_mfma_f32_16x16x32_bf16(a0, b0, acc[0], 0, 0, 0);
    acc[1] = __builtin_amdgcn_mfma_f32_16x16x32_bf16(a1, b0, acc[1], 0, 0, 0);
  }
  const float bo = bout[o];
#pragma unroll
  for (int mt = 0; mt < 2; ++mt)
#pragma unroll
    for (int r = 0; r < 4; ++r) {
      const int b = 16 * mt + 4 * kg + r;
      out[((size_t)b * NT + t) * NOUT + o] = acc[mt][r] + bo;
    }
}

// ---------------- launch ----------------------------------------------------
// ws: [0, 65,536,000)             jx bf16 [NT][NB][NN]  (post-scan: wouth @ +0... NO:
//     wouth now lives in the Hex tail region so k_prep_out can run BEFORE k_scan)
//     [65,536,000, 131,072,000)   Hh bf16 [NT][NB][NN]  (pre-scan: winh @ +0)
//     [131,072,000, 131,203,072)  Hex u32 [2][NB][NN]   (4B self-tagged atoms)
//     [131,203,072, 131,268,608)  wouth bf16 [NOUT][NN] (64KB, independent)
extern "C" void kernel_launch(void* const* d_in, const int* in_sizes, int n_in,
                              void* d_out, int out_size, void* d_ws, size_t ws_size,
                              hipStream_t stream) {
  (void)in_sizes; (void)n_in; (void)out_size;
  const float* x    = (const float*)d_in[0];
  const float* Wrec = (const float*)d_in[1];
  const float* brec = (const float*)d_in[2];
  const float* Win  = (const float*)d_in[3];
  const float* Wout = (const float*)d_in[4];
  const float* bout = (const float*)d_in[5];
  float* out = (float*)d_out;

  if (ws_size < 131268608ULL) return;  // visible failure beacon

  char* ws = (char*)d_ws;
  u16* jx    = (u16*)ws;
  u16* Hh    = (u16*)(ws + 65536000);
  u32* Hex   = (u32*)(ws + 131072000);
  u16* wouth = (u16*)(ws + 131203072); // independent region: prep overlaps scan
  u16* winh  = (u16*)(ws + 65536000);  // overlays Hh (dead until k_scan)

  hipMemsetAsync(Hex, 0, 2 * PAR, stream);   // kill poison/cross-launch tag aliases
  k_prep_in<<<dim3((NN * NIN + 255) / 256), dim3(256), 0, stream>>>(Win, winh);
  k_prep_out<<<dim3((NOUT * NN + 255) / 256), dim3(256), 0, stream>>>(Wout, wouth);
  k_in<<<dim3(NT), dim3(256), 0, stream>>>(x, winh, jx);
  k_scan<<<dim3(64), dim3(256), 0, stream>>>(Wrec, brec, jx, Hex, Hh);
  k_out<<<dim3(NT), dim3(256), 0, stream>>>(Hh, wouth, bout, out);
}

// Round 19
// 2524.327 us; speedup vs baseline: 1.6883x; 1.0001x over previous
//
#include <hip/hip_runtime.h>
#include <hip/hip_bf16.h>
#include <cstdint>

// RateModel: h_{s+1} = tanh(W_rec h_s + b_rec + W_in x_s); out = W_out h + b_out
// B=32, Nt=2000 (sequential), N=512, N_in=128, N_out=64.
//
// k_scan R18 = R17 (proven: 2532us k_scan; hi-only bf16 recurrence) + ledger fix:
//  - DEFERRED Hh STORE: the history store (plain, HBM) is issued AFTER the
//    next step's poll loads, and the first tag-check waits vmcnt(1) instead of
//    vmcnt(0). R17's step-top vmcnt(0) FIFO-drained the epilogue's Hh store
//    ack (~600-900cy HBM) before the polls could be consumed. Ledger at check
//    (oldest->newest): [publish, jx, A0, A1, Hh'] -> vmcnt(1) retires the 4
//    oldest. Out-of-order store retirement worst case leaves a poll unretired
//    -> stale register -> tag check FAILS -> vmcnt(0) retry corrects it
//    (self-validating; never wrong, at most one extra round). All loop VMEM is
//    inline-asm so the ledger is exact. Final step's Hh stored after the loop.
//  - k_prep_out launched before k_scan (overlap; it only needs Wout).
// Protocol (R4/R11/R13/R17-proven): 4B atoms [hi16|0|tag3], tag=step&7,
// sc0 sc1 (MALL; any WG placement); skew<=1 => stale tag differs by 2 mod 8
// => never false-validates; line-atomic tag check; Hex memsetAsync(0) per
// launch. Polls strictly serialized per address (R10 MSHR-merge). No in-flight
// asm dests across control flow (R12). Deterministic, replay-safe.

#define NB   32
#define NT   2000
#define NIN  128
#define NN   512
#define NOUT 64
#define NBNN (NB * NN)
#define PAR  65536            // bytes per parity slot (u32[32][512])

typedef unsigned short u16;
typedef unsigned int   u32;
typedef unsigned long long u64;
typedef __bf16 bf16x8 __attribute__((ext_vector_type(8)));
typedef float  f32x4  __attribute__((ext_vector_type(4)));
typedef u32    u32x4  __attribute__((ext_vector_type(4)));

static __device__ __forceinline__ u16 f2bf(float f) {
  return __builtin_bit_cast(u16, (__bf16)f);   // RNE
}
static __device__ __forceinline__ float bf2f(u16 u) {
  return (float)__builtin_bit_cast(__bf16, u);
}
static __device__ __forceinline__ void split_hl(float f, u16& hi, u16& lo) {
  const u32 u = __float_as_uint(f);
  hi = (u16)(u >> 16);                                   // truncated bf16
  lo = f2bf(f - __uint_as_float(u & 0xffff0000u));       // residual
}
static __device__ __forceinline__ float fast_tanh(float x) {
  const float xc = fminf(fmaxf(x, -12.f), 12.f);
  const float t = __builtin_amdgcn_exp2f(xc * 2.8853900817779268f); // 2*log2(e)
  return (t - 1.f) * __builtin_amdgcn_rcpf(t + 1.f);
}

// device-scope (MALL) 16B ops; vmcnt-only, invisible to compiler's wait model
static __device__ __forceinline__ u32x4 ld_dev16(const void* p) {
  u32x4 r;
  asm volatile("global_load_dwordx4 %0, %1, off sc0 sc1" : "=v"(r) : "v"(p) : "memory");
  return r;
}
static __device__ __forceinline__ void st_dev16(void* p, u32x4 v) {
  asm volatile("global_store_dwordx4 %0, %1, off sc0 sc1" :: "v"(p), "v"(v) : "memory");
}
static __device__ __forceinline__ void st_plain8(void* p, u64 v) {
  asm volatile("global_store_dwordx2 %0, %1, off" :: "v"(p), "v"(v) : "memory");
}
static __device__ __forceinline__ void ld_u16a(u32& d, const void* p) {
  asm volatile("global_load_ushort %0, %1, off" : "=v"(d) : "v"(p) : "memory");
}
// line-atomic: one tag per 16B line suffices (16B store = 1 MALL transaction)
static __device__ __forceinline__ bool tags2(u32x4 a, u32x4 b, u32 want) {
  return ((a.x & 7u) == want) & ((b.x & 7u) == want);
}

// ---------------- prep: bf16 weight tables --------------------------------
__global__ __launch_bounds__(256) void k_prep_in(const float* __restrict__ Win,
                                                 u16* __restrict__ winh) {
  const int e = blockIdx.x * 256 + threadIdx.x;
  if (e < NN * NIN) winh[e] = f2bf(Win[e]);
}
__global__ __launch_bounds__(256) void k_prep_out(const float* __restrict__ Wout,
                                                  u16* __restrict__ wouth) {
  const int e = blockIdx.x * 256 + threadIdx.x;
  if (e < NOUT * NN) wouth[e] = f2bf(Wout[e]);
}

// ---------------- K1 (MFMA): jx[t][b][n] = sum_k x[b][t][k] * Win[n][k] ----
__global__ __launch_bounds__(256) void k_in(const float* __restrict__ x,
                                            const u16* __restrict__ winh,
                                            u16* __restrict__ jx) {
  const int t = blockIdx.x;
  const int tid = threadIdx.x;
  const int wv = tid >> 6, lane = tid & 63;
  __shared__ u16 Xh[NB][136];
  __shared__ u16 Xl[NB][136];
  {
    const int b = tid >> 3, k0 = (tid & 7) * 16;
    const float* xp = x + ((size_t)b * NT + t) * NIN + k0;
    u16 hb[16], lb[16];
#pragma unroll
    for (int j = 0; j < 16; ++j) split_hl(xp[j], hb[j], lb[j]);
    *(uint4*)&Xh[b][k0]     = *(uint4*)&hb[0];
    *(uint4*)&Xh[b][k0 + 8] = *(uint4*)&hb[8];
    *(uint4*)&Xl[b][k0]     = *(uint4*)&lb[0];
    *(uint4*)&Xl[b][k0 + 8] = *(uint4*)&lb[8];
  }
  __syncthreads();

  const int r15 = lane & 15, kg = lane >> 4;
  const int n0 = 128 * wv;
  f32x4 acc[2][8];
#pragma unroll
  for (int mt = 0; mt < 2; ++mt)
#pragma unroll
    for (int nt = 0; nt < 8; ++nt) acc[mt][nt] = (f32x4){0.f, 0.f, 0.f, 0.f};

#pragma unroll
  for (int kt = 0; kt < 4; ++kt) {
    const int ko = 32 * kt + 8 * kg;
    const bf16x8 ah0 = *(const bf16x8*)&Xh[r15][ko];
    const bf16x8 ah1 = *(const bf16x8*)&Xh[16 + r15][ko];
    const bf16x8 al0 = *(const bf16x8*)&Xl[r15][ko];
    const bf16x8 al1 = *(const bf16x8*)&Xl[16 + r15][ko];
#pragma unroll
    for (int nt = 0; nt < 8; ++nt) {
      const int n = n0 + 16 * nt + r15;
      const bf16x8 bh = *(const bf16x8*)(winh + (size_t)n * NIN + ko);
      acc[0][nt] = __builtin_amdgcn_mfma_f32_16x16x32_bf16(ah0, bh, acc[0][nt], 0, 0, 0);
      acc[1][nt] = __builtin_amdgcn_mfma_f32_16x16x32_bf16(ah1, bh, acc[1][nt], 0, 0, 0);
      acc[0][nt] = __builtin_amdgcn_mfma_f32_16x16x32_bf16(al0, bh, acc[0][nt], 0, 0, 0);
      acc[1][nt] = __builtin_amdgcn_mfma_f32_16x16x32_bf16(al1, bh, acc[1][nt], 0, 0, 0);
    }
  }
#pragma unroll
  for (int mt = 0; mt < 2; ++mt)
#pragma unroll
    for (int nt = 0; nt < 8; ++nt) {
      const int n = n0 + 16 * nt + r15;
#pragma unroll
      for (int r = 0; r < 4; ++r) {
        const int b = 16 * mt + 4 * kg + r;
        jx[((size_t)t * NB + b) * NN + n] = f2bf(acc[mt][nt][r]);
      }
    }
}

// ---------------- K2: sequential scan --------------------------------------
__global__ __launch_bounds__(256) void k_scan(const float* __restrict__ Wrec,
                                              const float* __restrict__ brec,
                                              const u16* __restrict__ jx,
                                              u32* Hex,             // [2][NB][NN] 4B atoms
                                              u16* __restrict__ Hh) // [NT][NB][NN]
{
  const int wg = blockIdx.x;
  const int g = wg & 7, i = wg >> 3;
  const int tid = threadIdx.x;
  const int wv = tid >> 6, lane = tid & 63;

  // stride 528 u16 = 264 dw == 8 (mod 32): B-frag ds_read_b128 2-way -> free (m136)
  __shared__ u16 SHhi[2][4][528];
  __shared__ float Pj[2][4][64];

  const int r15 = lane & 15, kg = lane >> 4;
  const int t64 = tid & 63;
  const float brv = brec[64 * i + t64];

  // resident A-frags: row = lane&15, k = 8*kg + j (contig-8)
  const int arow = 64 * i + 16 * wv + r15;
  bf16x8 afrag[16];
#pragma unroll
  for (int kt = 0; kt < 16; ++kt) {
    const float* wp = Wrec + (size_t)arow * NN + 32 * kt + 8 * kg;
    bf16x8 a;
#pragma unroll
    for (int j = 0; j < 8; ++j) a[j] = (__bf16)wp[j];
    afrag[kt] = a;
  }

  const int sc = wv;                 // staged chain (== wave)
  const int cc = r15;                // D col = chain (valid < 4)
  const int rb = 16 * wv + 4 * kg;   // D row base within WG slice
  const int gch = 4 * g + cc;
  const int ro = 64 * i + rb;        // global rows ro..ro+3 (ro%4==0)
  const bool ownrow = ((t64 >> 3) == i);  // polled rows are own WG's rows

  char* HexB_ = (char*)Hex;
  // consumer: rows 8*t64..+7 of chain sc -> 32B contiguous
  const char* cb = HexB_ + ((size_t)(4 * g + sc) * NN + 8 * t64) * 4;
  // producer: rows ro..ro+3 of chain gch -> one 16B line
  char* pb = HexB_ + ((size_t)gch * NN + ro) * 4;

  const char* jp = (const char*)jx + ((size_t)(NB + 4 * g + sc) * NN + 64 * i + t64) * 2;
  u16* hb = Hh + (size_t)gch * NN + ro;

  const float jxv0 = bf2f(jx[(size_t)(4 * g + sc) * NN + 64 * i + t64]);
  u32 jxu = 0;
  u64 hprev = 0;                      // deferred Hh payload (computed value)
  u16* hbprev = hb;                   // deferred Hh address

  for (int s = 0; s < NT; ++s) {
    const int slot = s & 1;
    if (s > 0) {
      // R13-proven pacing, then polls; deferred Hh store goes AFTER the polls
      asm volatile("s_sleep 5" :::);
      const char* cbs = cb + (slot ? PAR : 0);
      const u32 want = (u32)s & 7u;
      u32x4 A0 = ld_dev16(cbs);
      u32x4 A1 = ld_dev16(cbs + 16);
      if (cc < 4) st_plain8(hbprev, hprev);             // prev step's history
      // ledger (oldest->newest): [publish, jx, A0, A1, Hh] -> retire 4 oldest
      asm volatile("s_waitcnt vmcnt(1)" ::: "memory");
      __builtin_amdgcn_sched_barrier(0);
      Pj[slot][sc][t64] = __uint_as_float(jxu << 16) + brv;  // jx retired
      bool ok = ownrow | tags2(A0, A1, want);
      int guard = 1 << 16;                               // anti-hang only
      while (!__all(ok) && --guard) {
        A0 = ld_dev16(cbs);
        A1 = ld_dev16(cbs + 16);
        asm volatile("s_waitcnt vmcnt(0)" ::: "memory"); // retries drain all
        __builtin_amdgcn_sched_barrier(0);
        ok = ownrow | tags2(A0, A1, want);
      }
      if (!ownrow) {
        // unpack: atom = [hi16 | 0 | tag3]; rows ascend A0.x..A1.w (hi only)
        const u32x4 hw = {(A0.x >> 16) | (A0.y & 0xffff0000u),
                          (A0.z >> 16) | (A0.w & 0xffff0000u),
                          (A1.x >> 16) | (A1.y & 0xffff0000u),
                          (A1.z >> 16) | (A1.w & 0xffff0000u)};
        *(u32x4*)&SHhi[slot][sc][8 * t64] = hw;
      }
    } else {
      Pj[0][sc][t64] = jxv0 + brv;
    }

    // single barrier per step: drains only LDS writes (globals are vmcnt-only)
    asm volatile("s_waitcnt lgkmcnt(0)" ::: "memory");
    __builtin_amdgcn_s_barrier();
    __builtin_amdgcn_sched_barrier(0);

    // 4 independent MFMA chains (K-quarters), hi-only
    f32x4 a0 = {0.f, 0.f, 0.f, 0.f}, a1 = {0.f, 0.f, 0.f, 0.f};
    f32x4 a2 = {0.f, 0.f, 0.f, 0.f}, a3 = {0.f, 0.f, 0.f, 0.f};
    if (s > 0) {
      const int c4 = cc & 3;
#pragma unroll
      for (int kt = 0; kt < 4; ++kt) {
        const int k0 = 32 * kt + 8 * kg;
        const bf16x8 b0 = *(const bf16x8*)&SHhi[slot][c4][k0];
        const bf16x8 b1 = *(const bf16x8*)&SHhi[slot][c4][k0 + 128];
        const bf16x8 b2 = *(const bf16x8*)&SHhi[slot][c4][k0 + 256];
        const bf16x8 b3 = *(const bf16x8*)&SHhi[slot][c4][k0 + 384];
        a0 = __builtin_amdgcn_mfma_f32_16x16x32_bf16(afrag[kt],      b0, a0, 0, 0, 0);
        a1 = __builtin_amdgcn_mfma_f32_16x16x32_bf16(afrag[kt + 4],  b1, a1, 0, 0, 0);
        a2 = __builtin_amdgcn_mfma_f32_16x16x32_bf16(afrag[kt + 8],  b2, a2, 0, 0, 0);
        a3 = __builtin_amdgcn_mfma_f32_16x16x32_bf16(afrag[kt + 12], b3, a3, 0, 0, 0);
      }
    }
    const f32x4 acc = (a0 + a1) + (a2 + a3);

    // epilogue: publish FIRST (peers' critical path), self-stage own rows,
    // DEFER the Hh store to next step (after its polls), then jx prefetch
    const int nsl = (s + 1) & 1;
    if (cc < 4) {
      const u32 tg = (u32)(s + 1) & 7u;
      u32 atom[4];
      u16 hp[4];
#pragma unroll
      for (int r = 0; r < 4; ++r) {
        const float pre = acc[r] + Pj[slot][cc][rb + r];
        const float h = fast_tanh(pre);
        const u32 uh = __float_as_uint(h);
        hp[r] = (u16)(uh >> 16);
        atom[r] = (uh & 0xffff0000u) | tg;     // [hi16 | 0 | tag3]
      }
      st_dev16(pb + (nsl ? PAR : 0), (u32x4){atom[0], atom[1], atom[2], atom[3]});
      uint2 hw2;
      hw2.x = (u32)hp[0] | ((u32)hp[1] << 16);
      hw2.y = (u32)hp[2] | ((u32)hp[3] << 16);
      *(uint2*)&SHhi[nsl][cc][ro] = hw2;       // self-stage (never polled)
      hprev = (u64)hw2.x | ((u64)hw2.y << 32); // defer history store
      hbprev = hb;
    }
    hb += NBNN;

    // jx prefetch for next step (different address; no poll hazard)
    if (s + 1 < NT) {
      ld_u16a(jxu, jp);
      jp += 2 * NBNN;
    }
  }
  // final step's deferred history store
  if (cc < 4) st_plain8(hbprev, hprev);
}

// ---------------- K3 (MFMA): out[b][t][o] = sum_n Hh[t][b][n]*Wout[o][n] + bout[o]
__global__ __launch_bounds__(256) void k_out(const u16* __restrict__ Hh,
                                             const u16* __restrict__ wouth,
                                             const float* __restrict__ bout,
                                             float* __restrict__ out) {
  const int t = blockIdx.x;
  const int tid = threadIdx.x;
  const int wv = tid >> 6, lane = tid & 63;
  __shared__ u16 Ah[NB][528];
  {
    const int b = tid >> 3, k0 = (tid & 7) * 64;
    const u16* hp = Hh + ((size_t)t * NB + b) * NN + k0;
#pragma unroll
    for (int j = 0; j < 8; ++j)
      *(uint4*)&Ah[b][k0 + 8 * j] = *(const uint4*)(hp + 8 * j);
  }
  __syncthreads();

  const int r15 = lane & 15, kg = lane >> 4;
  const int o = 16 * wv + r15;
  f32x4 acc[2] = {{0.f, 0.f, 0.f, 0.f}, {0.f, 0.f, 0.f, 0.f}};
#pragma unroll
  for (int kt = 0; kt < 16; ++kt) {
    const int ko = 32 * kt + 8 * kg;
    const bf16x8 b0 = *(const bf16x8*)(wouth + (size_t)o * NN + ko);
    const bf16x8 a0 = *(const bf16x8*)&Ah[r15][ko];
    const bf16x8 a1 = *(const bf16x8*)&Ah[16 + r15][ko];
    acc[0] = __builtin_amdgcn_mfma_f32_16x16x32_bf16(a0, b0, acc[0], 0, 0, 0);
    acc[1] = __builtin_amdgcn_mfma_f32_16x16x32_bf16(a1, b0, acc[1], 0, 0, 0);
  }
  const float bo = bout[o];
#pragma unroll
  for (int mt = 0; mt < 2; ++mt)
#pragma unroll
    for (int r = 0; r < 4; ++r) {
      const int b = 16 * mt + 4 * kg + r;
      out[((size_t)b * NT + t) * NOUT + o] = acc[mt][r] + bo;
    }
}

// ---------------- launch ----------------------------------------------------
// ws: [0, 65,536,000)             jx bf16 [NT][NB][NN]  (post-scan: wouth @ +0... NO:
//     wouth now lives in the Hex tail region so k_prep_out can run BEFORE k_scan)
//     [65,536,000, 131,072,000)   Hh bf16 [NT][NB][NN]  (pre-scan: winh @ +0)
//     [131,072,000, 131,203,072)  Hex u32 [2][NB][NN]   (4B self-tagged atoms)
//     [131,203,072, 131,268,608)  wouth bf16 [NOUT][NN] (64KB, independent)
extern "C" void kernel_launch(void* const* d_in, const int* in_sizes, int n_in,
                              void* d_out, int out_size, void* d_ws, size_t ws_size,
                              hipStream_t stream) {
  (void)in_sizes; (void)n_in; (void)out_size;
  const float* x    = (const float*)d_in[0];
  const float* Wrec = (const float*)d_in[1];
  const float* brec = (const float*)d_in[2];
  const float* Win  = (const float*)d_in[3];
  const float* Wout = (const float*)d_in[4];
  const float* bout = (const float*)d_in[5];
  float* out = (float*)d_out;

  if (ws_size < 131268608ULL) return;  // visible failure beacon

  char* ws = (char*)d_ws;
  u16* jx    = (u16*)ws;
  u16* Hh    = (u16*)(ws + 65536000);
  u32* Hex   = (u32*)(ws + 131072000);
  u16* wouth = (u16*)(ws + 131203072); // independent region: prep overlaps scan
  u16* winh  = (u16*)(ws + 65536000);  // overlays Hh (dead until k_scan)

  hipMemsetAsync(Hex, 0, 2 * PAR, stream);   // kill poison/cross-launch tag aliases
  k_prep_in<<<dim3((NN * NIN + 255) / 256), dim3(256), 0, stream>>>(Win, winh);
  k_prep_out<<<dim3((NOUT * NN + 255) / 256), dim3(256), 0, stream>>>(Wout, wouth);
  k_in<<<dim3(NT), dim3(256), 0, stream>>>(x, winh, jx);
  k_scan<<<dim3(64), dim3(256), 0, stream>>>(Wrec, brec, jx, Hex, Hh);
  k_out<<<dim3(NT), dim3(256), 0, stream>>>(Hh, wouth, bout, out);
}